// Round 2
// baseline (7253.007 us; speedup 1.0000x reference)
//
#include <hip/hip_runtime.h>
#include <math.h>

#define T_LEN 4096
#define D_MODEL 1280
#define H_NUM 16
#define HD 80
#define HALF 40
#define N_QKV (3*D_MODEL)

// ---------------- rope tables: cs/sn[t][d] = cos/sin(rope[t][d]) ----------------
__global__ void rope_table(const float* __restrict__ rope,
                           float* __restrict__ cs, float* __restrict__ sn)
{
    int i = blockIdx.x * 256 + threadIdx.x;
    if (i < T_LEN * HALF) {
        float a = rope[i];
        cs[i] = cosf(a);
        sn[i] = sinf(a);
    }
}

// ---------------- GEMM1: qkv = x @ Wqkv + bqkv, scattered RAW to q/k/v [H][T][HD] ----------------
__global__ __launch_bounds__(256) void gemm_qkv(const float* __restrict__ A,
                                                const float* __restrict__ B,
                                                const float* __restrict__ bias,
                                                float* __restrict__ qb,
                                                float* __restrict__ kb,
                                                float* __restrict__ vb)
{
    const int N = N_QKV, K = D_MODEL;
    const int BK = 16;
    __shared__ float As[64][BK + 1];
    __shared__ float Bs[BK][64 + 1];
    int tid = threadIdx.x;
    int tx = tid % 16, ty = tid / 16;
    int m0 = blockIdx.y * 64, n0 = blockIdx.x * 64;
    float acc[4][4] = {};
    for (int k0 = 0; k0 < K; k0 += BK) {
        #pragma unroll
        for (int i = 0; i < 4; ++i) {
            int idx = tid + i * 256;
            int r = idx / BK, c = idx % BK;
            As[r][c] = A[(size_t)(m0 + r) * K + k0 + c];
        }
        #pragma unroll
        for (int i = 0; i < 4; ++i) {
            int idx = tid + i * 256;
            int r = idx / 64, c = idx % 64;
            Bs[r][c] = B[(size_t)(k0 + r) * N + n0 + c];
        }
        __syncthreads();
        #pragma unroll
        for (int kk = 0; kk < BK; ++kk) {
            float a[4], b[4];
            #pragma unroll
            for (int i = 0; i < 4; ++i) a[i] = As[ty * 4 + i][kk];
            #pragma unroll
            for (int j = 0; j < 4; ++j) b[j] = Bs[kk][tx * 4 + j];
            #pragma unroll
            for (int i = 0; i < 4; ++i)
                #pragma unroll
                for (int j = 0; j < 4; ++j) acc[i][j] += a[i] * b[j];
        }
        __syncthreads();
    }
    #pragma unroll
    for (int i = 0; i < 4; ++i) {
        int m = m0 + ty * 4 + i;
        #pragma unroll
        for (int j = 0; j < 4; ++j) {
            int n = n0 + tx * 4 + j;
            float val = acc[i][j] + bias[n];
            int sel = n / D_MODEL;
            int rem = n - sel * D_MODEL;
            int h = rem / HD, d = rem % HD;
            float* dst = (sel == 0) ? qb : ((sel == 1) ? kb : vb);
            dst[((size_t)h * T_LEN + m) * HD + d] = val;
        }
    }
}

// ---------------- Flash attention v2: rope fused at load, wave-parallel softmax ----------------
__global__ __launch_bounds__(256) void flash_attn2(const float* __restrict__ qb,
                                                   const float* __restrict__ kb,
                                                   const float* __restrict__ vb,
                                                   const float* __restrict__ cs,
                                                   const float* __restrict__ sn,
                                                   float* __restrict__ out)
{
    const int h = blockIdx.y;
    const int q0 = blockIdx.x * 64;
    __shared__ float Qs[64][81];   // roped Q tile
    __shared__ float KVs[64][81];  // holds K (roped) during scores, V during PV
    __shared__ float Ps[64][65];   // softmax probabilities
    const int tid = threadIdx.x;
    const int tx = tid % 16, ty = tid / 16;
    const float scale = 0.11180339887498949f;  // 1/sqrt(80)

    // Load Q tile with rope applied from tables.
    for (int i = tid; i < 64 * HD; i += 256) {
        int r = i / HD, c = i % HD;
        int t = q0 + r;
        size_t base = ((size_t)h * T_LEN + t) * HD;
        float val;
        if (c < HALF) {
            val = qb[base + c] * cs[t * HALF + c] - qb[base + c + HALF] * sn[t * HALF + c];
        } else {
            int c2 = c - HALF;
            val = qb[base + c2] * sn[t * HALF + c2] + qb[base + c] * cs[t * HALF + c2];
        }
        Qs[r][c] = val;
    }

    float m_run[4], l_run[4];
    #pragma unroll
    for (int i = 0; i < 4; ++i) { m_run[i] = -1e30f; l_run[i] = 0.f; }
    float oacc[4][5] = {};

    for (int kt = 0; kt < T_LEN / 64; ++kt) {
        // Load K tile (roped) into KVs.
        for (int i = tid; i < 64 * HD; i += 256) {
            int r = i / HD, c = i % HD;
            int t = kt * 64 + r;
            size_t base = ((size_t)h * T_LEN + t) * HD;
            float val;
            if (c < HALF) {
                val = kb[base + c] * cs[t * HALF + c] - kb[base + c + HALF] * sn[t * HALF + c];
            } else {
                int c2 = c - HALF;
                val = kb[base + c2] * sn[t * HALF + c2] + kb[base + c] * cs[t * HALF + c2];
            }
            KVs[r][c] = val;
        }
        __syncthreads();  // B1: K visible (covers Qs on first iter too)

        // Scores: 4x4 micro-tile in registers. rows ty*4+i, cols tx*4+j.
        float sacc[4][4] = {};
        #pragma unroll 8
        for (int c = 0; c < HD; ++c) {
            float a[4], b[4];
            #pragma unroll
            for (int i = 0; i < 4; ++i) a[i] = Qs[ty * 4 + i][c];
            #pragma unroll
            for (int j = 0; j < 4; ++j) b[j] = KVs[tx * 4 + j][c];
            #pragma unroll
            for (int i = 0; i < 4; ++i)
                #pragma unroll
                for (int j = 0; j < 4; ++j) sacc[i][j] += a[i] * b[j];
        }
        __syncthreads();  // B2: all waves done reading K

        // Load V tile into KVs (overlaps with register-local softmax below).
        for (int i = tid; i < 64 * HD; i += 256) {
            int r = i / HD, c = i % HD;
            KVs[r][c] = vb[((size_t)h * T_LEN + kt * 64 + r) * HD + c];
        }

        // Wave-parallel online softmax. Row r = ty*4+i lives in the 16 lanes
        // sharing ty (lanes ty*16..ty*16+15 of one wave); shfl_xor 1/2/4/8
        // reduces across them. m_run/l_run kept redundantly per lane.
        float al[4];
        #pragma unroll
        for (int i = 0; i < 4; ++i) {
            float mx = -1e30f;
            #pragma unroll
            for (int j = 0; j < 4; ++j) {
                sacc[i][j] *= scale;
                mx = fmaxf(mx, sacc[i][j]);
            }
            mx = fmaxf(mx, __shfl_xor(mx, 1));
            mx = fmaxf(mx, __shfl_xor(mx, 2));
            mx = fmaxf(mx, __shfl_xor(mx, 4));
            mx = fmaxf(mx, __shfl_xor(mx, 8));
            float m_new = fmaxf(m_run[i], mx);
            al[i] = __expf(m_run[i] - m_new);
            float ps = 0.f;
            #pragma unroll
            for (int j = 0; j < 4; ++j) {
                float p = __expf(sacc[i][j] - m_new);
                Ps[ty * 4 + i][tx * 4 + j] = p;
                ps += p;
            }
            ps += __shfl_xor(ps, 1);
            ps += __shfl_xor(ps, 2);
            ps += __shfl_xor(ps, 4);
            ps += __shfl_xor(ps, 8);
            l_run[i] = l_run[i] * al[i] + ps;
            m_run[i] = m_new;
        }
        __syncthreads();  // B3: V visible (Ps is wave-local: writer ty-group == reader ty-group)

        // PV: rows ty*4+i, cols tx*5+c5.
        #pragma unroll
        for (int i = 0; i < 4; ++i) {
            int r = ty * 4 + i;
            #pragma unroll
            for (int c5 = 0; c5 < 5; ++c5) {
                int col = tx * 5 + c5;
                float acc = oacc[i][c5] * al[i];
                for (int j = 0; j < 64; ++j) acc += Ps[r][j] * KVs[j][col];
                oacc[i][c5] = acc;
            }
        }
        __syncthreads();  // B4: PV done before next K overwrites KVs
    }

    #pragma unroll
    for (int i = 0; i < 4; ++i) {
        int t = q0 + ty * 4 + i;
        float inv = 1.0f / l_run[i];
        #pragma unroll
        for (int c5 = 0; c5 < 5; ++c5) {
            int col = tx * 5 + c5;
            out[(size_t)t * D_MODEL + h * HD + col] = oacc[i][c5] * inv;
        }
    }
}

// ---------------- GEMM2: out = attn @ Wo + bo ----------------
__global__ __launch_bounds__(256) void gemm_out(const float* __restrict__ A,
                                                const float* __restrict__ B,
                                                const float* __restrict__ bias,
                                                float* __restrict__ C)
{
    const int N = D_MODEL, K = D_MODEL;
    const int BK = 16;
    __shared__ float As[64][BK + 1];
    __shared__ float Bs[BK][64 + 1];
    int tid = threadIdx.x;
    int tx = tid % 16, ty = tid / 16;
    int m0 = blockIdx.y * 64, n0 = blockIdx.x * 64;
    float acc[4][4] = {};
    for (int k0 = 0; k0 < K; k0 += BK) {
        #pragma unroll
        for (int i = 0; i < 4; ++i) {
            int idx = tid + i * 256;
            int r = idx / BK, c = idx % BK;
            As[r][c] = A[(size_t)(m0 + r) * K + k0 + c];
        }
        #pragma unroll
        for (int i = 0; i < 4; ++i) {
            int idx = tid + i * 256;
            int r = idx / 64, c = idx % 64;
            Bs[r][c] = B[(size_t)(k0 + r) * N + n0 + c];
        }
        __syncthreads();
        #pragma unroll
        for (int kk = 0; kk < BK; ++kk) {
            float a[4], b[4];
            #pragma unroll
            for (int i = 0; i < 4; ++i) a[i] = As[ty * 4 + i][kk];
            #pragma unroll
            for (int j = 0; j < 4; ++j) b[j] = Bs[kk][tx * 4 + j];
            #pragma unroll
            for (int i = 0; i < 4; ++i)
                #pragma unroll
                for (int j = 0; j < 4; ++j) acc[i][j] += a[i] * b[j];
        }
        __syncthreads();
    }
    #pragma unroll
    for (int i = 0; i < 4; ++i) {
        int m = m0 + ty * 4 + i;
        #pragma unroll
        for (int j = 0; j < 4; ++j) {
            int n = n0 + tx * 4 + j;
            C[(size_t)m * N + n] = acc[i][j] + bias[n];
        }
    }
}

extern "C" void kernel_launch(void* const* d_in, const int* in_sizes, int n_in,
                              void* d_out, int out_size, void* d_ws, size_t ws_size,
                              hipStream_t stream)
{
    const float* x    = (const float*)d_in[0];
    const float* rope = (const float*)d_in[1];
    const float* Wqkv = (const float*)d_in[2];
    const float* bqkv = (const float*)d_in[3];
    const float* Wo   = (const float*)d_in[4];
    const float* bo   = (const float*)d_in[5];
    float* out = (float*)d_out;
    float* ws  = (float*)d_ws;

    const size_t per = (size_t)H_NUM * T_LEN * HD;  // 5,242,880 floats
    float* qb   = ws;
    float* kb   = ws + per;
    float* vb   = ws + 2 * per;
    float* attn = ws + 3 * per;
    float* cs   = ws + 4 * per;
    float* sn   = cs + (size_t)T_LEN * HALF;

    rope_table<<<(T_LEN * HALF + 255) / 256, 256, 0, stream>>>(rope, cs, sn);

    gemm_qkv<<<dim3(N_QKV / 64, T_LEN / 64), 256, 0, stream>>>(x, Wqkv, bqkv, qb, kb, vb);

    flash_attn2<<<dim3(T_LEN / 64, H_NUM), 256, 0, stream>>>(qb, kb, vb, cs, sn, attn);

    gemm_out<<<dim3(D_MODEL / 64, T_LEN / 64), 256, 0, stream>>>(attn, Wo, bo, out);
}

// Round 3
// 1363.344 us; speedup vs baseline: 5.3200x; 5.3200x over previous
//
#include <hip/hip_runtime.h>
#include <math.h>

#define T_LEN 4096
#define D_MODEL 1280
#define H_NUM 16
#define HD 80
#define HALF 40
#define N_QKV (3*D_MODEL)

typedef short short8 __attribute__((ext_vector_type(8)));
typedef short short4v __attribute__((ext_vector_type(4)));
typedef float f32x4 __attribute__((ext_vector_type(4)));

static __device__ __forceinline__ unsigned short f2bf(float f) {
    unsigned int u = __builtin_bit_cast(unsigned int, f);
    unsigned int r = (u + 0x7FFFu + ((u >> 16) & 1u)) >> 16;
    return (unsigned short)r;
}

// ---------------- rope tables ----------------
__global__ void rope_table(const float* __restrict__ rope,
                           float* __restrict__ cs, float* __restrict__ sn)
{
    int i = blockIdx.x * 256 + threadIdx.x;
    if (i < T_LEN * HALF) {
        float a = rope[i];
        cs[i] = cosf(a);
        sn[i] = sinf(a);
    }
}

// ---------------- GEMM1: qkv = x @ Wqkv + bqkv, scatter fp32 to q/k/v [H][T][HD] ----------------
__global__ __launch_bounds__(256) void gemm_qkv(const float* __restrict__ A,
                                                const float* __restrict__ B,
                                                const float* __restrict__ bias,
                                                float* __restrict__ qb,
                                                float* __restrict__ kb,
                                                float* __restrict__ vb)
{
    const int N = N_QKV, K = D_MODEL;
    const int BK = 16;
    __shared__ float As[64][BK + 1];
    __shared__ float Bs[BK][64 + 1];
    int tid = threadIdx.x;
    int tx = tid % 16, ty = tid / 16;
    int m0 = blockIdx.y * 64, n0 = blockIdx.x * 64;
    float acc[4][4] = {};
    for (int k0 = 0; k0 < K; k0 += BK) {
        #pragma unroll
        for (int i = 0; i < 4; ++i) {
            int idx = tid + i * 256;
            int r = idx / BK, c = idx % BK;
            As[r][c] = A[(size_t)(m0 + r) * K + k0 + c];
        }
        #pragma unroll
        for (int i = 0; i < 4; ++i) {
            int idx = tid + i * 256;
            int r = idx / 64, c = idx % 64;
            Bs[r][c] = B[(size_t)(k0 + r) * N + n0 + c];
        }
        __syncthreads();
        #pragma unroll
        for (int kk = 0; kk < BK; ++kk) {
            float a[4], b[4];
            #pragma unroll
            for (int i = 0; i < 4; ++i) a[i] = As[ty * 4 + i][kk];
            #pragma unroll
            for (int j = 0; j < 4; ++j) b[j] = Bs[kk][tx * 4 + j];
            #pragma unroll
            for (int i = 0; i < 4; ++i)
                #pragma unroll
                for (int j = 0; j < 4; ++j) acc[i][j] += a[i] * b[j];
        }
        __syncthreads();
    }
    #pragma unroll
    for (int i = 0; i < 4; ++i) {
        int m = m0 + ty * 4 + i;
        #pragma unroll
        for (int j = 0; j < 4; ++j) {
            int n = n0 + tx * 4 + j;
            float val = acc[i][j] + bias[n];
            int sel = n / D_MODEL;
            int rem = n - sel * D_MODEL;
            int h = rem / HD, d = rem % HD;
            float* dst = (sel == 0) ? qb : ((sel == 1) ? kb : vb);
            dst[((size_t)h * T_LEN + m) * HD + d] = val;
        }
    }
}

// ---------------- v transpose + bf16: vt[h][f][t] ----------------
__global__ __launch_bounds__(256) void v_prep(const float* __restrict__ vb,
                                              unsigned short* __restrict__ vt)
{
    const int h = blockIdx.y;
    const int t0 = blockIdx.x * 64;
    __shared__ float tileS[64][81];
    int tid = threadIdx.x;
    for (int i = tid; i < 64 * HD; i += 256) {
        int r = i / HD, f = i % HD;
        tileS[r][f] = vb[((size_t)h * T_LEN + t0 + r) * HD + f];
    }
    __syncthreads();
    for (int i = tid; i < HD * 64; i += 256) {
        int f = i / 64, tt = i % 64;
        vt[((size_t)h * HD + f) * T_LEN + t0 + tt] = f2bf(tileS[tt][f]);
    }
}

// ---------------- rope + bf16 for q,k ----------------
__global__ __launch_bounds__(256) void qk_prep(const float* __restrict__ qb,
                                               const float* __restrict__ kb,
                                               const float* __restrict__ cs,
                                               const float* __restrict__ sn,
                                               unsigned short* __restrict__ qbf,
                                               unsigned short* __restrict__ kbf)
{
    int idx = blockIdx.x * 256 + threadIdx.x;
    const int total = H_NUM * T_LEN * HALF;
    if (idx >= total) return;
    int d = idx % HALF;
    int t = (idx / HALF) % T_LEN;
    int h = idx / (HALF * T_LEN);
    float c = cs[t * HALF + d], s = sn[t * HALF + d];
    size_t base = ((size_t)h * T_LEN + t) * HD;
    float qr = qb[base + d], qi = qb[base + d + HALF];
    qbf[base + d]        = f2bf(qr * c - qi * s);
    qbf[base + d + HALF] = f2bf(qr * s + qi * c);
    float kr = kb[base + d], ki = kb[base + d + HALF];
    kbf[base + d]        = f2bf(kr * c - ki * s);
    kbf[base + d + HALF] = f2bf(kr * s + ki * c);
}

// ---------------- Flash attention v3: bf16 MFMA ----------------
// 4 waves/block; wave wq owns Q rows q0+wq*16 .. +15. KV tile = 64.
// MFMA 16x16x32 layouts: A: row=lane&15, k=8*(lane>>4)+j ; B: col=lane&15,
// k=8*(lane>>4)+i ; C/D: row=4*(lane>>4)+r, col=lane&15  (learn_hip m89).
__global__ __launch_bounds__(256) void flash_mfma(const unsigned short* __restrict__ qbf,
                                                  const unsigned short* __restrict__ kbf,
                                                  const unsigned short* __restrict__ vt,
                                                  float* __restrict__ out)
{
    const int h = blockIdx.y;
    const int q0 = blockIdx.x * 64;
    const int tid = threadIdx.x;
    const int wq = tid >> 6;
    const int lane = tid & 63;
    const int g = lane >> 4;
    const int c = lane & 15;

    __shared__ unsigned short Ks[64][104];     // [kv][feature 0..95], pad->104 (2-way banks)
    __shared__ unsigned short Vs[HD][72];      // [feature][kv 0..63], pad->72
    __shared__ unsigned short Ps[4][16][72];   // wave-private P: [q-row 0..15][kv], pad->72

    // zero K pad cols 80..95 once (never overwritten)
    for (int i = tid; i < 64 * 16; i += 256)
        Ks[i >> 4][80 + (i & 15)] = 0;

    // Q fragments (zero-padded to k=96)
    short8 qf[3];
    {
        const unsigned short* qp = qbf + ((size_t)h * T_LEN + q0 + wq * 16 + c) * HD;
        #pragma unroll
        for (int ch = 0; ch < 3; ++ch) {
            int k = ch * 32 + 8 * g;
            if (k < HD) qf[ch] = *(const short8*)(qp + k);
            else        qf[ch] = (short8)(short)0;
        }
    }

    f32x4 oacc[5];
    #pragma unroll
    for (int m = 0; m < 5; ++m) oacc[m] = (f32x4)(0.f);
    float m_run[4], l_run[4];
    #pragma unroll
    for (int r = 0; r < 4; ++r) { m_run[r] = -1e30f; l_run[r] = 0.f; }
    const float scale = 0.11180339887498949f;  // 1/sqrt(80)

    for (int kt = 0; kt < T_LEN / 64; ++kt) {
        // stage K tile (64x80) and V^T tile (80x64), 8B vector chunks
        {
            const unsigned short* kp = kbf + ((size_t)h * T_LEN + kt * 64) * HD;
            for (int i = tid; i < 1280; i += 256) {
                int r = i / 20, cc = (i % 20) * 4;
                *(short4v*)&Ks[r][cc] = *(const short4v*)(kp + r * HD + cc);
            }
            const unsigned short* vp = vt + (size_t)h * HD * T_LEN + kt * 64;
            for (int i = tid; i < 1280; i += 256) {
                int r = i / 16, cc = (i % 16) * 4;
                *(short4v*)&Vs[r][cc] = *(const short4v*)(vp + (size_t)r * T_LEN + cc);
            }
        }
        __syncthreads();  // K/V visible

        // S = Q K^T : 4 column tiles of 16x16, K=96 in 3 chunks
        f32x4 s[4];
        #pragma unroll
        for (int t = 0; t < 4; ++t) {
            f32x4 acc = (f32x4)(0.f);
            #pragma unroll
            for (int ch = 0; ch < 3; ++ch) {
                short8 b = *(const short8*)&Ks[t * 16 + c][ch * 32 + 8 * g];
                acc = __builtin_amdgcn_mfma_f32_16x16x32_bf16(qf[ch], b, acc, 0, 0, 0);
            }
            s[t] = acc;
        }

        // wave-parallel online softmax; rows 4g+r live in 16 lanes sharing g
        float al[4];
        #pragma unroll
        for (int r = 0; r < 4; ++r) {
            float mx = -1e30f;
            #pragma unroll
            for (int t = 0; t < 4; ++t) { s[t][r] *= scale; mx = fmaxf(mx, s[t][r]); }
            mx = fmaxf(mx, __shfl_xor(mx, 1));
            mx = fmaxf(mx, __shfl_xor(mx, 2));
            mx = fmaxf(mx, __shfl_xor(mx, 4));
            mx = fmaxf(mx, __shfl_xor(mx, 8));
            float m_new = fmaxf(m_run[r], mx);
            al[r] = __expf(m_run[r] - m_new);
            float ps = 0.f;
            #pragma unroll
            for (int t = 0; t < 4; ++t) {
                float p = __expf(s[t][r] - m_new);
                s[t][r] = p;
                ps += p;
            }
            ps += __shfl_xor(ps, 1);
            ps += __shfl_xor(ps, 2);
            ps += __shfl_xor(ps, 4);
            ps += __shfl_xor(ps, 8);
            l_run[r] = l_run[r] * al[r] + ps;
            m_run[r] = m_new;
        }

        // write P to wave-private LDS (bf16): row=q (4g+r), col=kv (16t+c)
        #pragma unroll
        for (int t = 0; t < 4; ++t)
            #pragma unroll
            for (int r = 0; r < 4; ++r)
                Ps[wq][4 * g + r][t * 16 + c] = f2bf(s[t][r]);

        // rescale O accumulators (rows 4g+r are lane-local)
        #pragma unroll
        for (int m = 0; m < 5; ++m)
            #pragma unroll
            for (int r = 0; r < 4; ++r)
                oacc[m][r] *= al[r];

        // O += P V : A = P (16x64), B = V^T-tile rows as B[k=kv][col=feature]
        #pragma unroll
        for (int ch = 0; ch < 2; ++ch) {
            short8 a = *(const short8*)&Ps[wq][c][ch * 32 + 8 * g];
            #pragma unroll
            for (int m = 0; m < 5; ++m) {
                short8 b = *(const short8*)&Vs[m * 16 + c][ch * 32 + 8 * g];
                oacc[m] = __builtin_amdgcn_mfma_f32_16x16x32_bf16(a, b, oacc[m], 0, 0, 0);
            }
        }
        __syncthreads();  // all waves done with Ks/Vs before next stage
    }

    #pragma unroll
    for (int r = 0; r < 4; ++r) {
        float inv = 1.0f / l_run[r];
        int t = q0 + wq * 16 + 4 * g + r;
        #pragma unroll
        for (int m = 0; m < 5; ++m)
            out[(size_t)t * D_MODEL + h * HD + m * 16 + c] = oacc[m][r] * inv;
    }
}

// ---------------- GEMM2: out = attn @ Wo + bo ----------------
__global__ __launch_bounds__(256) void gemm_out(const float* __restrict__ A,
                                                const float* __restrict__ B,
                                                const float* __restrict__ bias,
                                                float* __restrict__ C)
{
    const int N = D_MODEL, K = D_MODEL;
    const int BK = 16;
    __shared__ float As[64][BK + 1];
    __shared__ float Bs[BK][64 + 1];
    int tid = threadIdx.x;
    int tx = tid % 16, ty = tid / 16;
    int m0 = blockIdx.y * 64, n0 = blockIdx.x * 64;
    float acc[4][4] = {};
    for (int k0 = 0; k0 < K; k0 += BK) {
        #pragma unroll
        for (int i = 0; i < 4; ++i) {
            int idx = tid + i * 256;
            int r = idx / BK, c = idx % BK;
            As[r][c] = A[(size_t)(m0 + r) * K + k0 + c];
        }
        #pragma unroll
        for (int i = 0; i < 4; ++i) {
            int idx = tid + i * 256;
            int r = idx / 64, c = idx % 64;
            Bs[r][c] = B[(size_t)(k0 + r) * N + n0 + c];
        }
        __syncthreads();
        #pragma unroll
        for (int kk = 0; kk < BK; ++kk) {
            float a[4], b[4];
            #pragma unroll
            for (int i = 0; i < 4; ++i) a[i] = As[ty * 4 + i][kk];
            #pragma unroll
            for (int j = 0; j < 4; ++j) b[j] = Bs[kk][tx * 4 + j];
            #pragma unroll
            for (int i = 0; i < 4; ++i)
                #pragma unroll
                for (int j = 0; j < 4; ++j) acc[i][j] += a[i] * b[j];
        }
        __syncthreads();
    }
    #pragma unroll
    for (int i = 0; i < 4; ++i) {
        int m = m0 + ty * 4 + i;
        #pragma unroll
        for (int j = 0; j < 4; ++j) {
            int n = n0 + tx * 4 + j;
            C[(size_t)m * N + n] = acc[i][j] + bias[n];
        }
    }
}

extern "C" void kernel_launch(void* const* d_in, const int* in_sizes, int n_in,
                              void* d_out, int out_size, void* d_ws, size_t ws_size,
                              hipStream_t stream)
{
    const float* x    = (const float*)d_in[0];
    const float* rope = (const float*)d_in[1];
    const float* Wqkv = (const float*)d_in[2];
    const float* bqkv = (const float*)d_in[3];
    const float* Wo   = (const float*)d_in[4];
    const float* bo   = (const float*)d_in[5];
    float* out = (float*)d_out;
    float* ws  = (float*)d_ws;

    const size_t per = (size_t)H_NUM * T_LEN * HD;   // 5,242,880 floats
    const size_t tab = (size_t)T_LEN * HALF;         // 163,840 floats
    float* qb = ws;                                  // fp32 q   [0, per)
    float* kb = ws + per;                            // fp32 k
    float* vb = ws + 2 * per;                        // fp32 v
    float* cs = ws + 3 * per;                        // cos table
    float* sn = cs + tab;                            // sin table
    unsigned short* vt  = (unsigned short*)(sn + tab);       // bf16 v^T [H][80][T]
    // qbf/kbf alias vb (dead after v_prep); attn aliases qb (dead after qk_prep)
    unsigned short* qbf = (unsigned short*)vb;
    unsigned short* kbf = qbf + per;
    float* attn = qb;

    rope_table<<<(T_LEN * HALF + 255) / 256, 256, 0, stream>>>(rope, cs, sn);

    gemm_qkv<<<dim3(N_QKV / 64, T_LEN / 64), 256, 0, stream>>>(x, Wqkv, bqkv, qb, kb, vb);

    v_prep<<<dim3(T_LEN / 64, H_NUM), 256, 0, stream>>>(vb, vt);

    qk_prep<<<(H_NUM * T_LEN * HALF + 255) / 256, 256, 0, stream>>>(qb, kb, cs, sn, qbf, kbf);

    flash_mfma<<<dim3(T_LEN / 64, H_NUM), 256, 0, stream>>>(qbf, kbf, vt, attn);

    gemm_out<<<dim3(D_MODEL / 64, T_LEN / 64), 256, 0, stream>>>(attn, Wo, bo, out);
}

// Round 4
// 462.079 us; speedup vs baseline: 15.6965x; 2.9505x over previous
//
#include <hip/hip_runtime.h>
#include <math.h>

#define T_LEN 4096
#define D_MODEL 1280
#define H_NUM 16
#define HD 80
#define HALF 40
#define N_QKV (3*D_MODEL)

typedef short short8 __attribute__((ext_vector_type(8)));
typedef short short4v __attribute__((ext_vector_type(4)));
typedef float f32x4 __attribute__((ext_vector_type(4)));
typedef float float4v __attribute__((ext_vector_type(4)));
typedef unsigned short ushort_t;

static __device__ __forceinline__ unsigned short f2bf(float f) {
    unsigned int u = __builtin_bit_cast(unsigned int, f);
    unsigned int r = (u + 0x7FFFu + ((u >> 16) & 1u)) >> 16;
    return (unsigned short)r;
}
static __device__ __forceinline__ float bf2f(unsigned short u) {
    return __builtin_bit_cast(float, (unsigned int)u << 16);
}

#define GLOAD16(gp, lp) \
    __builtin_amdgcn_global_load_lds((const __attribute__((address_space(1))) void*)(gp), \
                                     (__attribute__((address_space(3))) void*)(lp), 16, 0, 0)

// ---------------- rope tables ----------------
__global__ void rope_table(const float* __restrict__ rope,
                           float* __restrict__ cs, float* __restrict__ sn)
{
    int i = blockIdx.x * 256 + threadIdx.x;
    if (i < T_LEN * HALF) {
        float a = rope[i];
        cs[i] = cosf(a);
        sn[i] = sinf(a);
    }
}

// ---------------- fp32 -> bf16 elementwise (n % 1024 == 0) ----------------
__global__ __launch_bounds__(256) void cvt_bf16(const float* __restrict__ in,
                                                ushort_t* __restrict__ out)
{
    int i = (blockIdx.x * 256 + threadIdx.x) * 4;
    float4v v = *(const float4v*)&in[i];
    short4v o;
    o[0] = (short)f2bf(v[0]); o[1] = (short)f2bf(v[1]);
    o[2] = (short)f2bf(v[2]); o[3] = (short)f2bf(v[3]);
    *(short4v*)&out[i] = o;
}

// ---------------- fp32 [R][C] -> bf16 [C][R] transpose ----------------
__global__ __launch_bounds__(256) void transpose_cvt(const float* __restrict__ in,
                                                     ushort_t* __restrict__ out,
                                                     int R, int C)
{
    __shared__ float tile[64][65];
    int r0 = blockIdx.y * 64, c0 = blockIdx.x * 64;
    int tid = threadIdx.x;
    for (int i = tid; i < 4096; i += 256) {
        int r = i >> 6, c = i & 63;
        tile[r][c] = in[(size_t)(r0 + r) * C + c0 + c];
    }
    __syncthreads();
    for (int i = tid; i < 4096; i += 256) {
        int r = i >> 6, c = i & 63;
        out[(size_t)(c0 + r) * R + r0 + c] = f2bf(tile[c][r]);
    }
}

// ---------------- GEMM1 (bf16 MFMA, m97 structure): qkv = x @ Wqkv + b ----------------
// A = xbf [4096][1280] bf16 row-major, B = Wt [3840][1280] bf16 (pre-transposed).
// Epilogue: q,k -> raw bf16 [H][T][80]; v -> bf16 transposed vt [H][80][T].
__global__ __launch_bounds__(256) void gemm_qkv_mfma(const ushort_t* __restrict__ xbf,
                                                     const ushort_t* __restrict__ Wt,
                                                     const float* __restrict__ bias,
                                                     ushort_t* __restrict__ qraw,
                                                     ushort_t* __restrict__ kraw,
                                                     ushort_t* __restrict__ vt)
{
    __shared__ ushort_t As[128 * 32];
    __shared__ ushort_t Bs[128 * 32];
    const int tid = threadIdx.x;
    const int wave = tid >> 6, lane = tid & 63;
    const int g = lane >> 4, c = lane & 15;
    const int wr = wave >> 1, wc = wave & 1;
    const int m0 = blockIdx.y * 128, n0 = blockIdx.x * 128;
    const int K = D_MODEL;

    f32x4 acc[4][4];
    #pragma unroll
    for (int i = 0; i < 4; ++i)
        #pragma unroll
        for (int j = 0; j < 4; ++j) acc[i][j] = (f32x4)(0.f);

    for (int k0 = 0; k0 < K; k0 += 32) {
        // stage A,B tiles: 512 chunks of 16B each; wave w stages chunks [w*128, w*128+128)
        #pragma unroll
        for (int q = 0; q < 2; ++q) {
            int j = wave * 128 + q * 64 + lane;
            int row = j >> 2, col8 = (j & 3) * 8;
            GLOAD16(xbf + (size_t)(m0 + row) * K + k0 + col8, &As[(wave * 2 + q) * 512]);
            GLOAD16(Wt  + (size_t)(n0 + row) * K + k0 + col8, &Bs[(wave * 2 + q) * 512]);
        }
        __syncthreads();

        short8 a[4], b[4];
        #pragma unroll
        for (int mi = 0; mi < 4; ++mi)
            a[mi] = *(const short8*)&As[(wr * 64 + mi * 16 + c) * 32 + g * 8];
        #pragma unroll
        for (int ni = 0; ni < 4; ++ni)
            b[ni] = *(const short8*)&Bs[(wc * 64 + ni * 16 + c) * 32 + g * 8];
        #pragma unroll
        for (int mi = 0; mi < 4; ++mi)
            #pragma unroll
            for (int ni = 0; ni < 4; ++ni)
                acc[mi][ni] = __builtin_amdgcn_mfma_f32_16x16x32_bf16(a[mi], b[ni], acc[mi][ni], 0, 0, 0);
        __syncthreads();
    }

    // epilogue: C/D layout row = 4g+r, col = c (per 16x16 tile)
    const int sel = n0 / D_MODEL;             // 128 | 1280 -> uniform per block
    #pragma unroll
    for (int mi = 0; mi < 4; ++mi) {
        int tbase = m0 + wr * 64 + mi * 16 + 4 * g;
        #pragma unroll
        for (int ni = 0; ni < 4; ++ni) {
            int n = n0 + wc * 64 + ni * 16 + c;
            float bv = bias[n];
            int rem = n - sel * D_MODEL;
            int h = rem / HD, d = rem % HD;
            if (sel < 2) {
                ushort_t* dst = sel ? kraw : qraw;
                #pragma unroll
                for (int r = 0; r < 4; ++r)
                    dst[((size_t)h * T_LEN + tbase + r) * HD + d] = f2bf(acc[mi][ni][r] + bv);
            } else {
                short4v o;
                #pragma unroll
                for (int r = 0; r < 4; ++r) o[r] = (short)f2bf(acc[mi][ni][r] + bv);
                *(short4v*)&vt[((size_t)h * HD + d) * T_LEN + tbase] = o;
            }
        }
    }
}

// ---------------- rope on raw bf16 q,k -> roped bf16 ----------------
__global__ __launch_bounds__(256) void qk_prep(const ushort_t* __restrict__ qraw,
                                               const ushort_t* __restrict__ kraw,
                                               const float* __restrict__ cs,
                                               const float* __restrict__ sn,
                                               ushort_t* __restrict__ qbf,
                                               ushort_t* __restrict__ kbf)
{
    int idx = blockIdx.x * 256 + threadIdx.x;
    int d = idx % HALF;
    int t = (idx / HALF) % T_LEN;
    int h = idx / (HALF * T_LEN);
    float c = cs[t * HALF + d], s = sn[t * HALF + d];
    size_t base = ((size_t)h * T_LEN + t) * HD;
    float qr = bf2f(qraw[base + d]), qi = bf2f(qraw[base + d + HALF]);
    qbf[base + d]        = f2bf(qr * c - qi * s);
    qbf[base + d + HALF] = f2bf(qr * s + qi * c);
    float kr = bf2f(kraw[base + d]), ki = bf2f(kraw[base + d + HALF]);
    kbf[base + d]        = f2bf(kr * c - ki * s);
    kbf[base + d + HALF] = f2bf(kr * s + ki * c);
}

// ---------------- Flash attention (bf16 MFMA), output bf16 ----------------
__global__ __launch_bounds__(256) void flash_mfma(const ushort_t* __restrict__ qbf,
                                                  const ushort_t* __restrict__ kbf,
                                                  const ushort_t* __restrict__ vt,
                                                  ushort_t* __restrict__ attn_bf)
{
    const int h = blockIdx.y;
    const int q0 = blockIdx.x * 64;
    const int tid = threadIdx.x;
    const int wq = tid >> 6;
    const int lane = tid & 63;
    const int g = lane >> 4;
    const int c = lane & 15;

    __shared__ ushort_t Ks[64][104];
    __shared__ ushort_t Vs[HD][72];
    __shared__ ushort_t Ps[4][16][72];

    for (int i = tid; i < 64 * 16; i += 256)
        Ks[i >> 4][80 + (i & 15)] = 0;

    short8 qf[3];
    {
        const ushort_t* qp = qbf + ((size_t)h * T_LEN + q0 + wq * 16 + c) * HD;
        #pragma unroll
        for (int ch = 0; ch < 3; ++ch) {
            int k = ch * 32 + 8 * g;
            if (k < HD) qf[ch] = *(const short8*)(qp + k);
            else        qf[ch] = (short8)(short)0;
        }
    }

    f32x4 oacc[5];
    #pragma unroll
    for (int m = 0; m < 5; ++m) oacc[m] = (f32x4)(0.f);
    float m_run[4], l_run[4];
    #pragma unroll
    for (int r = 0; r < 4; ++r) { m_run[r] = -1e30f; l_run[r] = 0.f; }
    const float scale = 0.11180339887498949f;

    for (int kt = 0; kt < T_LEN / 64; ++kt) {
        {
            const ushort_t* kp = kbf + ((size_t)h * T_LEN + kt * 64) * HD;
            for (int i = tid; i < 1280; i += 256) {
                int r = i / 20, cc = (i % 20) * 4;
                *(short4v*)&Ks[r][cc] = *(const short4v*)(kp + r * HD + cc);
            }
            const ushort_t* vp = vt + (size_t)h * HD * T_LEN + kt * 64;
            for (int i = tid; i < 1280; i += 256) {
                int r = i / 16, cc = (i % 16) * 4;
                *(short4v*)&Vs[r][cc] = *(const short4v*)(vp + (size_t)r * T_LEN + cc);
            }
        }
        __syncthreads();

        f32x4 s[4];
        #pragma unroll
        for (int t = 0; t < 4; ++t) {
            f32x4 acc = (f32x4)(0.f);
            #pragma unroll
            for (int ch = 0; ch < 3; ++ch) {
                short8 b = *(const short8*)&Ks[t * 16 + c][ch * 32 + 8 * g];
                acc = __builtin_amdgcn_mfma_f32_16x16x32_bf16(qf[ch], b, acc, 0, 0, 0);
            }
            s[t] = acc;
        }

        float al[4];
        #pragma unroll
        for (int r = 0; r < 4; ++r) {
            float mx = -1e30f;
            #pragma unroll
            for (int t = 0; t < 4; ++t) { s[t][r] *= scale; mx = fmaxf(mx, s[t][r]); }
            mx = fmaxf(mx, __shfl_xor(mx, 1));
            mx = fmaxf(mx, __shfl_xor(mx, 2));
            mx = fmaxf(mx, __shfl_xor(mx, 4));
            mx = fmaxf(mx, __shfl_xor(mx, 8));
            float m_new = fmaxf(m_run[r], mx);
            al[r] = __expf(m_run[r] - m_new);
            float ps = 0.f;
            #pragma unroll
            for (int t = 0; t < 4; ++t) {
                float p = __expf(s[t][r] - m_new);
                s[t][r] = p;
                ps += p;
            }
            ps += __shfl_xor(ps, 1);
            ps += __shfl_xor(ps, 2);
            ps += __shfl_xor(ps, 4);
            ps += __shfl_xor(ps, 8);
            l_run[r] = l_run[r] * al[r] + ps;
            m_run[r] = m_new;
        }

        #pragma unroll
        for (int t = 0; t < 4; ++t)
            #pragma unroll
            for (int r = 0; r < 4; ++r)
                Ps[wq][4 * g + r][t * 16 + c] = f2bf(s[t][r]);

        #pragma unroll
        for (int m = 0; m < 5; ++m)
            #pragma unroll
            for (int r = 0; r < 4; ++r)
                oacc[m][r] *= al[r];

        #pragma unroll
        for (int ch = 0; ch < 2; ++ch) {
            short8 a = *(const short8*)&Ps[wq][c][ch * 32 + 8 * g];
            #pragma unroll
            for (int m = 0; m < 5; ++m) {
                short8 b = *(const short8*)&Vs[m * 16 + c][ch * 32 + 8 * g];
                oacc[m] = __builtin_amdgcn_mfma_f32_16x16x32_bf16(a, b, oacc[m], 0, 0, 0);
            }
        }
        __syncthreads();
    }

    #pragma unroll
    for (int r = 0; r < 4; ++r) {
        float inv = 1.0f / l_run[r];
        int t = q0 + wq * 16 + 4 * g + r;
        #pragma unroll
        for (int m = 0; m < 5; ++m)
            attn_bf[(size_t)t * D_MODEL + h * HD + m * 16 + c] = f2bf(oacc[m][r] * inv);
    }
}

// ---------------- GEMM2 (bf16 MFMA): out = attn @ Wo + bo, fp32 out ----------------
__global__ __launch_bounds__(256) void gemm_out_mfma(const ushort_t* __restrict__ Abf,
                                                     const ushort_t* __restrict__ Bt,
                                                     const float* __restrict__ bias,
                                                     float* __restrict__ C)
{
    __shared__ ushort_t As[128 * 32];
    __shared__ ushort_t Bs[128 * 32];
    const int tid = threadIdx.x;
    const int wave = tid >> 6, lane = tid & 63;
    const int g = lane >> 4, c = lane & 15;
    const int wr = wave >> 1, wc = wave & 1;
    const int m0 = blockIdx.y * 128, n0 = blockIdx.x * 128;
    const int K = D_MODEL;

    f32x4 acc[4][4];
    #pragma unroll
    for (int i = 0; i < 4; ++i)
        #pragma unroll
        for (int j = 0; j < 4; ++j) acc[i][j] = (f32x4)(0.f);

    for (int k0 = 0; k0 < K; k0 += 32) {
        #pragma unroll
        for (int q = 0; q < 2; ++q) {
            int j = wave * 128 + q * 64 + lane;
            int row = j >> 2, col8 = (j & 3) * 8;
            GLOAD16(Abf + (size_t)(m0 + row) * K + k0 + col8, &As[(wave * 2 + q) * 512]);
            GLOAD16(Bt  + (size_t)(n0 + row) * K + k0 + col8, &Bs[(wave * 2 + q) * 512]);
        }
        __syncthreads();

        short8 a[4], b[4];
        #pragma unroll
        for (int mi = 0; mi < 4; ++mi)
            a[mi] = *(const short8*)&As[(wr * 64 + mi * 16 + c) * 32 + g * 8];
        #pragma unroll
        for (int ni = 0; ni < 4; ++ni)
            b[ni] = *(const short8*)&Bs[(wc * 64 + ni * 16 + c) * 32 + g * 8];
        #pragma unroll
        for (int mi = 0; mi < 4; ++mi)
            #pragma unroll
            for (int ni = 0; ni < 4; ++ni)
                acc[mi][ni] = __builtin_amdgcn_mfma_f32_16x16x32_bf16(a[mi], b[ni], acc[mi][ni], 0, 0, 0);
        __syncthreads();
    }

    #pragma unroll
    for (int mi = 0; mi < 4; ++mi) {
        int tbase = m0 + wr * 64 + mi * 16 + 4 * g;
        #pragma unroll
        for (int ni = 0; ni < 4; ++ni) {
            int n = n0 + wc * 64 + ni * 16 + c;
            float bv = bias[n];
            #pragma unroll
            for (int r = 0; r < 4; ++r)
                C[(size_t)(tbase + r) * D_MODEL + n] = acc[mi][ni][r] + bv;
        }
    }
}

extern "C" void kernel_launch(void* const* d_in, const int* in_sizes, int n_in,
                              void* d_out, int out_size, void* d_ws, size_t ws_size,
                              hipStream_t stream)
{
    const float* x    = (const float*)d_in[0];
    const float* rope = (const float*)d_in[1];
    const float* Wqkv = (const float*)d_in[2];
    const float* bqkv = (const float*)d_in[3];
    const float* Wo   = (const float*)d_in[4];
    const float* bo   = (const float*)d_in[5];
    float* out = (float*)d_out;
    float* ws  = (float*)d_ws;

    const size_t per2 = 2621440;   // one [H][T][80] bf16 buffer, in float units
    const size_t wt_f = 2457600;   // Wqkv_t bf16 in float units (1280*3840/2)
    const size_t tab  = (size_t)T_LEN * HALF;

    ushort_t* qraw = (ushort_t*)ws;                    // dead after qk_prep
    ushort_t* kraw = (ushort_t*)(ws + per2);
    ushort_t* vt   = (ushort_t*)(ws + 2 * per2);
    ushort_t* xbf  = (ushort_t*)(ws + 3 * per2);       // dead after gemm1
    ushort_t* Wt   = (ushort_t*)(ws + 4 * per2);       // dead after gemm1
    float*    cs   = ws + 4 * per2 + wt_f;
    float*    sn   = cs + tab;
    ushort_t* qbf  = (ushort_t*)(sn + tab);            // dead after flash
    ushort_t* kbf  = (ushort_t*)(sn + tab + per2);
    ushort_t* attn_bf = qraw;                          // alias: qraw dead
    ushort_t* Wo_t = qbf;                              // alias: qbf dead (prep runs post-flash)

    rope_table<<<(T_LEN * HALF + 255) / 256, 256, 0, stream>>>(rope, cs, sn);

    cvt_bf16<<<(T_LEN * D_MODEL) / 1024, 256, 0, stream>>>(x, xbf);

    transpose_cvt<<<dim3(N_QKV / 64, D_MODEL / 64), 256, 0, stream>>>(Wqkv, Wt, D_MODEL, N_QKV);

    gemm_qkv_mfma<<<dim3(N_QKV / 128, T_LEN / 128), 256, 0, stream>>>(xbf, Wt, bqkv, qraw, kraw, vt);

    qk_prep<<<(H_NUM * T_LEN * HALF) / 256, 256, 0, stream>>>(qraw, kraw, cs, sn, qbf, kbf);

    flash_mfma<<<dim3(T_LEN / 64, H_NUM), 256, 0, stream>>>(qbf, kbf, vt, attn_bf);

    transpose_cvt<<<dim3(D_MODEL / 64, D_MODEL / 64), 256, 0, stream>>>(Wo, Wo_t, D_MODEL, D_MODEL);

    gemm_out_mfma<<<dim3(D_MODEL / 128, T_LEN / 128), 256, 0, stream>>>(attn_bf, Wo_t, bo, out);
}

// Round 5
// 343.854 us; speedup vs baseline: 21.0933x; 1.3438x over previous
//
#include <hip/hip_runtime.h>
#include <math.h>

#define T_LEN 4096
#define D_MODEL 1280
#define H_NUM 16
#define HD 80
#define HALF 40
#define N_QKV (3*D_MODEL)

typedef short short8 __attribute__((ext_vector_type(8)));
typedef short short4v __attribute__((ext_vector_type(4)));
typedef float f32x4 __attribute__((ext_vector_type(4)));
typedef float float4v __attribute__((ext_vector_type(4)));
typedef unsigned short ushort_t;

static __device__ __forceinline__ unsigned short f2bf(float f) {
    unsigned int u = __builtin_bit_cast(unsigned int, f);
    unsigned int r = (u + 0x7FFFu + ((u >> 16) & 1u)) >> 16;
    return (unsigned short)r;
}
static __device__ __forceinline__ float bf2f(unsigned short u) {
    return __builtin_bit_cast(float, (unsigned int)u << 16);
}

#define GLOAD16(gp, lp) \
    __builtin_amdgcn_global_load_lds((const __attribute__((address_space(1))) void*)(gp), \
                                     (__attribute__((address_space(3))) void*)(lp), 16, 0, 0)

// ---------------- rope tables ----------------
__global__ void rope_table(const float* __restrict__ rope,
                           float* __restrict__ cs, float* __restrict__ sn)
{
    int i = blockIdx.x * 256 + threadIdx.x;
    if (i < T_LEN * HALF) {
        float a = rope[i];
        cs[i] = cosf(a);
        sn[i] = sinf(a);
    }
}

// ---------------- fp32 -> bf16 elementwise (n % 1024 == 0) ----------------
__global__ __launch_bounds__(256) void cvt_bf16(const float* __restrict__ in,
                                                ushort_t* __restrict__ out)
{
    int i = (blockIdx.x * 256 + threadIdx.x) * 4;
    float4v v = *(const float4v*)&in[i];
    short4v o;
    o[0] = (short)f2bf(v[0]); o[1] = (short)f2bf(v[1]);
    o[2] = (short)f2bf(v[2]); o[3] = (short)f2bf(v[3]);
    *(short4v*)&out[i] = o;
}

// ---------------- fp32 [R][C] -> bf16 [C][R] transpose ----------------
__global__ __launch_bounds__(256) void transpose_cvt(const float* __restrict__ in,
                                                     ushort_t* __restrict__ out,
                                                     int R, int C)
{
    __shared__ float tile[64][65];
    int r0 = blockIdx.y * 64, c0 = blockIdx.x * 64;
    int tid = threadIdx.x;
    for (int i = tid; i < 4096; i += 256) {
        int r = i >> 6, c = i & 63;
        tile[r][c] = in[(size_t)(r0 + r) * C + c0 + c];
    }
    __syncthreads();
    for (int i = tid; i < 4096; i += 256) {
        int r = i >> 6, c = i & 63;
        out[(size_t)(c0 + r) * R + r0 + c] = f2bf(tile[c][r]);
    }
}

// ---------------- GEMM1 (bf16 MFMA, m97 structure): qkv = x @ Wqkv + b ----------------
__global__ __launch_bounds__(256) void gemm_qkv_mfma(const ushort_t* __restrict__ xbf,
                                                     const ushort_t* __restrict__ Wt,
                                                     const float* __restrict__ bias,
                                                     ushort_t* __restrict__ qraw,
                                                     ushort_t* __restrict__ kraw,
                                                     ushort_t* __restrict__ vt)
{
    __shared__ ushort_t As[128 * 32];
    __shared__ ushort_t Bs[128 * 32];
    const int tid = threadIdx.x;
    const int wave = tid >> 6, lane = tid & 63;
    const int g = lane >> 4, c = lane & 15;
    const int wr = wave >> 1, wc = wave & 1;
    const int m0 = blockIdx.y * 128, n0 = blockIdx.x * 128;
    const int K = D_MODEL;

    f32x4 acc[4][4];
    #pragma unroll
    for (int i = 0; i < 4; ++i)
        #pragma unroll
        for (int j = 0; j < 4; ++j) acc[i][j] = (f32x4)(0.f);

    for (int k0 = 0; k0 < K; k0 += 32) {
        #pragma unroll
        for (int q = 0; q < 2; ++q) {
            int j = wave * 128 + q * 64 + lane;
            int row = j >> 2, col8 = (j & 3) * 8;
            GLOAD16(xbf + (size_t)(m0 + row) * K + k0 + col8, &As[(wave * 2 + q) * 512]);
            GLOAD16(Wt  + (size_t)(n0 + row) * K + k0 + col8, &Bs[(wave * 2 + q) * 512]);
        }
        __syncthreads();

        short8 a[4], b[4];
        #pragma unroll
        for (int mi = 0; mi < 4; ++mi)
            a[mi] = *(const short8*)&As[(wr * 64 + mi * 16 + c) * 32 + g * 8];
        #pragma unroll
        for (int ni = 0; ni < 4; ++ni)
            b[ni] = *(const short8*)&Bs[(wc * 64 + ni * 16 + c) * 32 + g * 8];
        #pragma unroll
        for (int mi = 0; mi < 4; ++mi)
            #pragma unroll
            for (int ni = 0; ni < 4; ++ni)
                acc[mi][ni] = __builtin_amdgcn_mfma_f32_16x16x32_bf16(a[mi], b[ni], acc[mi][ni], 0, 0, 0);
        __syncthreads();
    }

    const int sel = n0 / D_MODEL;
    #pragma unroll
    for (int mi = 0; mi < 4; ++mi) {
        int tbase = m0 + wr * 64 + mi * 16 + 4 * g;
        #pragma unroll
        for (int ni = 0; ni < 4; ++ni) {
            int n = n0 + wc * 64 + ni * 16 + c;
            float bv = bias[n];
            int rem = n - sel * D_MODEL;
            int h = rem / HD, d = rem % HD;
            if (sel < 2) {
                ushort_t* dst = sel ? kraw : qraw;
                #pragma unroll
                for (int r = 0; r < 4; ++r)
                    dst[((size_t)h * T_LEN + tbase + r) * HD + d] = f2bf(acc[mi][ni][r] + bv);
            } else {
                short4v o;
                #pragma unroll
                for (int r = 0; r < 4; ++r) o[r] = (short)f2bf(acc[mi][ni][r] + bv);
                *(short4v*)&vt[((size_t)h * HD + d) * T_LEN + tbase] = o;
            }
        }
    }
}

// ---------------- rope on raw bf16 q,k; q gets scale*log2e folded in ----------------
__global__ __launch_bounds__(256) void qk_prep(const ushort_t* __restrict__ qraw,
                                               const ushort_t* __restrict__ kraw,
                                               const float* __restrict__ cs,
                                               const float* __restrict__ sn,
                                               ushort_t* __restrict__ qbf,
                                               ushort_t* __restrict__ kbf)
{
    const float SC = 0.16129842f;  // (1/sqrt(80)) * log2(e)
    int idx = blockIdx.x * 256 + threadIdx.x;
    int d = idx % HALF;
    int t = (idx / HALF) % T_LEN;
    int h = idx / (HALF * T_LEN);
    float c = cs[t * HALF + d], s = sn[t * HALF + d];
    size_t base = ((size_t)h * T_LEN + t) * HD;
    float qr = bf2f(qraw[base + d]), qi = bf2f(qraw[base + d + HALF]);
    qbf[base + d]        = f2bf((qr * c - qi * s) * SC);
    qbf[base + d + HALF] = f2bf((qr * s + qi * c) * SC);
    float kr = bf2f(kraw[base + d]), ki = bf2f(kraw[base + d + HALF]);
    kbf[base + d]        = f2bf(kr * c - ki * s);
    kbf[base + d + HALF] = f2bf(kr * s + ki * c);
}

// ---------------- Flash attention: swapped QK^T, in-lane softmax, defer-max ----------------
// S^T = mfma(A=K_frag, B=Q_frag): lane (g,c) ends up holding, per 16x16 tile t,
// scores S[q=c][kv=16t+4g+r] (r=0..3). Row-softmax = in-lane over 16 + shfl 16/32.
__global__ __launch_bounds__(256) void flash_mfma(const ushort_t* __restrict__ qbf,
                                                  const ushort_t* __restrict__ kbf,
                                                  const ushort_t* __restrict__ vt,
                                                  ushort_t* __restrict__ attn_bf)
{
    const int h = blockIdx.y;
    const int q0 = blockIdx.x * 64;
    const int tid = threadIdx.x;
    const int wq = tid >> 6;
    const int lane = tid & 63;
    const int g = lane >> 4;
    const int c = lane & 15;

    __shared__ ushort_t Ks[64][104];
    __shared__ ushort_t Vs[HD][72];
    __shared__ ushort_t Ps[4][16][72];

    for (int i = tid; i < 64 * 16; i += 256)
        Ks[i >> 4][80 + (i & 15)] = 0;

    short8 qf[3];
    {
        const ushort_t* qp = qbf + ((size_t)h * T_LEN + q0 + wq * 16 + c) * HD;
        #pragma unroll
        for (int ch = 0; ch < 3; ++ch) {
            int k = ch * 32 + 8 * g;
            if (k < HD) qf[ch] = *(const short8*)(qp + k);
            else        qf[ch] = (short8)(short)0;
        }
    }

    f32x4 oacc[5];
    #pragma unroll
    for (int m = 0; m < 5; ++m) oacc[m] = (f32x4)(0.f);
    float m_run = -1e30f, l_run = 0.f;

    for (int kt = 0; kt < T_LEN / 64; ++kt) {
        // stage K (64x80, pad 104) and V^T (80x64, pad 72) with 16B chunks
        {
            const ushort_t* kp = kbf + ((size_t)h * T_LEN + kt * 64) * HD;
            for (int i = tid; i < 640; i += 256) {
                int r = i / 10, cc = (i % 10) * 8;
                *(short8*)&Ks[r][cc] = *(const short8*)(kp + r * HD + cc);
            }
            const ushort_t* vp = vt + (size_t)h * HD * T_LEN + kt * 64;
            for (int i = tid; i < 640; i += 256) {
                int r = i >> 3, cc = (i & 7) * 8;
                *(short8*)&Vs[r][cc] = *(const short8*)(vp + (size_t)r * T_LEN + cc);
            }
        }
        __syncthreads();

        // S^T tiles: A = K rows (from LDS), B = Q (registers). Same addresses as before.
        f32x4 s[4];
        #pragma unroll
        for (int t = 0; t < 4; ++t) {
            f32x4 acc = (f32x4)(0.f);
            #pragma unroll
            for (int ch = 0; ch < 3; ++ch) {
                short8 a = *(const short8*)&Ks[t * 16 + c][ch * 32 + 8 * g];
                acc = __builtin_amdgcn_mfma_f32_16x16x32_bf16(a, qf[ch], acc, 0, 0, 0);
            }
            s[t] = acc;
        }

        // in-lane row max (16 scores for q=c), then combine across the 4 g-groups
        float mx = -1e30f;
        #pragma unroll
        for (int t = 0; t < 4; ++t)
            #pragma unroll
            for (int r = 0; r < 4; ++r) mx = fmaxf(mx, s[t][r]);
        mx = fmaxf(mx, __shfl_xor(mx, 16));
        mx = fmaxf(mx, __shfl_xor(mx, 32));

        // defer-max: only rescale when max grew by > 11 (log2 units); exact softmax
        float al = 1.f;
        if (!__all(mx - m_run <= 11.0f)) {
            float m_new = fmaxf(m_run, mx);
            al = __builtin_amdgcn_exp2f(m_run - m_new);
            m_run = m_new;
            #pragma unroll
            for (int r = 0; r < 4; ++r) {
                float alq = __shfl(al, 4 * g + r);   // al for q-row 4g+r
                #pragma unroll
                for (int m = 0; m < 5; ++m) oacc[m][r] *= alq;
            }
        }

        float ps = 0.f;
        #pragma unroll
        for (int t = 0; t < 4; ++t)
            #pragma unroll
            for (int r = 0; r < 4; ++r) {
                float p = __builtin_amdgcn_exp2f(s[t][r] - m_run);
                s[t][r] = p;
                ps += p;
            }
        ps += __shfl_xor(ps, 16);
        ps += __shfl_xor(ps, 32);
        l_run = l_run * al + ps;

        // P write: lane's kv 16t+4g+r are contiguous in r -> packed 8B stores
        #pragma unroll
        for (int t = 0; t < 4; ++t) {
            short4v pk;
            #pragma unroll
            for (int r = 0; r < 4; ++r) pk[r] = (short)f2bf(s[t][r]);
            *(short4v*)&Ps[wq][c][t * 16 + 4 * g] = pk;
        }

        // O += P V
        #pragma unroll
        for (int ch = 0; ch < 2; ++ch) {
            short8 a = *(const short8*)&Ps[wq][c][ch * 32 + 8 * g];
            #pragma unroll
            for (int m = 0; m < 5; ++m) {
                short8 b = *(const short8*)&Vs[m * 16 + c][ch * 32 + 8 * g];
                oacc[m] = __builtin_amdgcn_mfma_f32_16x16x32_bf16(a, b, oacc[m], 0, 0, 0);
            }
        }
        __syncthreads();
    }

    float linv = 1.0f / l_run;
    #pragma unroll
    for (int r = 0; r < 4; ++r) {
        float liq = __shfl(linv, 4 * g + r);   // 1/l for q-row 4g+r
        int t = q0 + wq * 16 + 4 * g + r;
        #pragma unroll
        for (int m = 0; m < 5; ++m)
            attn_bf[(size_t)t * D_MODEL + h * HD + m * 16 + c] = f2bf(oacc[m][r] * liq);
    }
}

// ---------------- GEMM2 (bf16 MFMA): out = attn @ Wo + bo, fp32 out ----------------
__global__ __launch_bounds__(256) void gemm_out_mfma(const ushort_t* __restrict__ Abf,
                                                     const ushort_t* __restrict__ Bt,
                                                     const float* __restrict__ bias,
                                                     float* __restrict__ C)
{
    __shared__ ushort_t As[128 * 32];
    __shared__ ushort_t Bs[128 * 32];
    const int tid = threadIdx.x;
    const int wave = tid >> 6, lane = tid & 63;
    const int g = lane >> 4, c = lane & 15;
    const int wr = wave >> 1, wc = wave & 1;
    const int m0 = blockIdx.y * 128, n0 = blockIdx.x * 128;
    const int K = D_MODEL;

    f32x4 acc[4][4];
    #pragma unroll
    for (int i = 0; i < 4; ++i)
        #pragma unroll
        for (int j = 0; j < 4; ++j) acc[i][j] = (f32x4)(0.f);

    for (int k0 = 0; k0 < K; k0 += 32) {
        #pragma unroll
        for (int q = 0; q < 2; ++q) {
            int j = wave * 128 + q * 64 + lane;
            int row = j >> 2, col8 = (j & 3) * 8;
            GLOAD16(Abf + (size_t)(m0 + row) * K + k0 + col8, &As[(wave * 2 + q) * 512]);
            GLOAD16(Bt  + (size_t)(n0 + row) * K + k0 + col8, &Bs[(wave * 2 + q) * 512]);
        }
        __syncthreads();

        short8 a[4], b[4];
        #pragma unroll
        for (int mi = 0; mi < 4; ++mi)
            a[mi] = *(const short8*)&As[(wr * 64 + mi * 16 + c) * 32 + g * 8];
        #pragma unroll
        for (int ni = 0; ni < 4; ++ni)
            b[ni] = *(const short8*)&Bs[(wc * 64 + ni * 16 + c) * 32 + g * 8];
        #pragma unroll
        for (int mi = 0; mi < 4; ++mi)
            #pragma unroll
            for (int ni = 0; ni < 4; ++ni)
                acc[mi][ni] = __builtin_amdgcn_mfma_f32_16x16x32_bf16(a[mi], b[ni], acc[mi][ni], 0, 0, 0);
        __syncthreads();
    }

    #pragma unroll
    for (int mi = 0; mi < 4; ++mi) {
        int tbase = m0 + wr * 64 + mi * 16 + 4 * g;
        #pragma unroll
        for (int ni = 0; ni < 4; ++ni) {
            int n = n0 + wc * 64 + ni * 16 + c;
            float bv = bias[n];
            #pragma unroll
            for (int r = 0; r < 4; ++r)
                C[(size_t)(tbase + r) * D_MODEL + n] = acc[mi][ni][r] + bv;
        }
    }
}

extern "C" void kernel_launch(void* const* d_in, const int* in_sizes, int n_in,
                              void* d_out, int out_size, void* d_ws, size_t ws_size,
                              hipStream_t stream)
{
    const float* x    = (const float*)d_in[0];
    const float* rope = (const float*)d_in[1];
    const float* Wqkv = (const float*)d_in[2];
    const float* bqkv = (const float*)d_in[3];
    const float* Wo   = (const float*)d_in[4];
    const float* bo   = (const float*)d_in[5];
    float* out = (float*)d_out;
    float* ws  = (float*)d_ws;

    const size_t per2 = 2621440;   // one [H][T][80] bf16 buffer, in float units
    const size_t wt_f = 2457600;   // Wqkv_t bf16 in float units
    const size_t tab  = (size_t)T_LEN * HALF;

    ushort_t* qraw = (ushort_t*)ws;
    ushort_t* kraw = (ushort_t*)(ws + per2);
    ushort_t* vt   = (ushort_t*)(ws + 2 * per2);
    ushort_t* xbf  = (ushort_t*)(ws + 3 * per2);
    ushort_t* Wt   = (ushort_t*)(ws + 4 * per2);
    float*    cs   = ws + 4 * per2 + wt_f;
    float*    sn   = cs + tab;
    ushort_t* qbf  = (ushort_t*)(sn + tab);
    ushort_t* kbf  = (ushort_t*)(sn + tab + per2);
    ushort_t* attn_bf = qraw;
    ushort_t* Wo_t = qbf;

    rope_table<<<(T_LEN * HALF + 255) / 256, 256, 0, stream>>>(rope, cs, sn);

    cvt_bf16<<<(T_LEN * D_MODEL) / 1024, 256, 0, stream>>>(x, xbf);

    transpose_cvt<<<dim3(N_QKV / 64, D_MODEL / 64), 256, 0, stream>>>(Wqkv, Wt, D_MODEL, N_QKV);

    gemm_qkv_mfma<<<dim3(N_QKV / 128, T_LEN / 128), 256, 0, stream>>>(xbf, Wt, bqkv, qraw, kraw, vt);

    qk_prep<<<(H_NUM * T_LEN * HALF) / 256, 256, 0, stream>>>(qraw, kraw, cs, sn, qbf, kbf);

    flash_mfma<<<dim3(T_LEN / 64, H_NUM), 256, 0, stream>>>(qbf, kbf, vt, attn_bf);

    transpose_cvt<<<dim3(D_MODEL / 64, D_MODEL / 64), 256, 0, stream>>>(Wo, Wo_t, D_MODEL, D_MODEL);

    gemm_out_mfma<<<dim3(D_MODEL / 128, T_LEN / 128), 256, 0, stream>>>(attn_bf, Wo_t, bo, out);
}

// Round 6
// 309.857 us; speedup vs baseline: 23.4076x; 1.1097x over previous
//
#include <hip/hip_runtime.h>
#include <math.h>

#define T_LEN 4096
#define D_MODEL 1280
#define H_NUM 16
#define HD 80
#define HALF 40
#define N_QKV (3*D_MODEL)

typedef short short8 __attribute__((ext_vector_type(8)));
typedef short short4v __attribute__((ext_vector_type(4)));
typedef float f32x4 __attribute__((ext_vector_type(4)));
typedef float float4v __attribute__((ext_vector_type(4)));
typedef unsigned short ushort_t;

static __device__ __forceinline__ unsigned short f2bf(float f) {
    unsigned int u = __builtin_bit_cast(unsigned int, f);
    unsigned int r = (u + 0x7FFFu + ((u >> 16) & 1u)) >> 16;
    return (unsigned short)r;
}
static __device__ __forceinline__ float bf2f(unsigned short u) {
    return __builtin_bit_cast(float, (unsigned int)u << 16);
}

#define GLOAD16(gp, lp) \
    __builtin_amdgcn_global_load_lds((const __attribute__((address_space(1))) void*)(gp), \
                                     (__attribute__((address_space(3))) void*)(lp), 16, 0, 0)

// ---------------- rope tables ----------------
__global__ void rope_table(const float* __restrict__ rope,
                           float* __restrict__ cs, float* __restrict__ sn)
{
    int i = blockIdx.x * 256 + threadIdx.x;
    if (i < T_LEN * HALF) {
        float a = rope[i];
        cs[i] = cosf(a);
        sn[i] = sinf(a);
    }
}

// ---------------- fp32 -> bf16 elementwise (n % 1024 == 0) ----------------
__global__ __launch_bounds__(256) void cvt_bf16(const float* __restrict__ in,
                                                ushort_t* __restrict__ out)
{
    int i = (blockIdx.x * 256 + threadIdx.x) * 4;
    float4v v = *(const float4v*)&in[i];
    short4v o;
    o[0] = (short)f2bf(v[0]); o[1] = (short)f2bf(v[1]);
    o[2] = (short)f2bf(v[2]); o[3] = (short)f2bf(v[3]);
    *(short4v*)&out[i] = o;
}

// ---------------- fp32 [R][C] -> bf16 [C][R] transpose ----------------
__global__ __launch_bounds__(256) void transpose_cvt(const float* __restrict__ in,
                                                     ushort_t* __restrict__ out,
                                                     int R, int C)
{
    __shared__ float tile[64][65];
    int r0 = blockIdx.y * 64, c0 = blockIdx.x * 64;
    int tid = threadIdx.x;
    for (int i = tid; i < 4096; i += 256) {
        int r = i >> 6, c = i & 63;
        tile[r][c] = in[(size_t)(r0 + r) * C + c0 + c];
    }
    __syncthreads();
    for (int i = tid; i < 4096; i += 256) {
        int r = i >> 6, c = i & 63;
        out[(size_t)(c0 + r) * R + r0 + c] = f2bf(tile[c][r]);
    }
}

// ---------------- GEMM1 (bf16 MFMA, m97 structure): qkv = x @ Wqkv + b ----------------
__global__ __launch_bounds__(256) void gemm_qkv_mfma(const ushort_t* __restrict__ xbf,
                                                     const ushort_t* __restrict__ Wt,
                                                     const float* __restrict__ bias,
                                                     ushort_t* __restrict__ qraw,
                                                     ushort_t* __restrict__ kraw,
                                                     ushort_t* __restrict__ vt)
{
    __shared__ ushort_t As[128 * 32];
    __shared__ ushort_t Bs[128 * 32];
    const int tid = threadIdx.x;
    const int wave = tid >> 6, lane = tid & 63;
    const int g = lane >> 4, c = lane & 15;
    const int wr = wave >> 1, wc = wave & 1;
    const int m0 = blockIdx.y * 128, n0 = blockIdx.x * 128;
    const int K = D_MODEL;

    f32x4 acc[4][4];
    #pragma unroll
    for (int i = 0; i < 4; ++i)
        #pragma unroll
        for (int j = 0; j < 4; ++j) acc[i][j] = (f32x4)(0.f);

    for (int k0 = 0; k0 < K; k0 += 32) {
        #pragma unroll
        for (int q = 0; q < 2; ++q) {
            int j = wave * 128 + q * 64 + lane;
            int row = j >> 2, col8 = (j & 3) * 8;
            GLOAD16(xbf + (size_t)(m0 + row) * K + k0 + col8, &As[(wave * 2 + q) * 512]);
            GLOAD16(Wt  + (size_t)(n0 + row) * K + k0 + col8, &Bs[(wave * 2 + q) * 512]);
        }
        __syncthreads();

        short8 a[4], b[4];
        #pragma unroll
        for (int mi = 0; mi < 4; ++mi)
            a[mi] = *(const short8*)&As[(wr * 64 + mi * 16 + c) * 32 + g * 8];
        #pragma unroll
        for (int ni = 0; ni < 4; ++ni)
            b[ni] = *(const short8*)&Bs[(wc * 64 + ni * 16 + c) * 32 + g * 8];
        #pragma unroll
        for (int mi = 0; mi < 4; ++mi)
            #pragma unroll
            for (int ni = 0; ni < 4; ++ni)
                acc[mi][ni] = __builtin_amdgcn_mfma_f32_16x16x32_bf16(a[mi], b[ni], acc[mi][ni], 0, 0, 0);
        __syncthreads();
    }

    const int sel = n0 / D_MODEL;
    #pragma unroll
    for (int mi = 0; mi < 4; ++mi) {
        int tbase = m0 + wr * 64 + mi * 16 + 4 * g;
        #pragma unroll
        for (int ni = 0; ni < 4; ++ni) {
            int n = n0 + wc * 64 + ni * 16 + c;
            float bv = bias[n];
            int rem = n - sel * D_MODEL;
            int h = rem / HD, d = rem % HD;
            if (sel < 2) {
                ushort_t* dst = sel ? kraw : qraw;
                #pragma unroll
                for (int r = 0; r < 4; ++r)
                    dst[((size_t)h * T_LEN + tbase + r) * HD + d] = f2bf(acc[mi][ni][r] + bv);
            } else {
                short4v o;
                #pragma unroll
                for (int r = 0; r < 4; ++r) o[r] = (short)f2bf(acc[mi][ni][r] + bv);
                *(short4v*)&vt[((size_t)h * HD + d) * T_LEN + tbase] = o;
            }
        }
    }
}

// ---------------- rope on raw bf16 q,k; q gets scale*log2e folded in ----------------
__global__ __launch_bounds__(256) void qk_prep(const ushort_t* __restrict__ qraw,
                                               const ushort_t* __restrict__ kraw,
                                               const float* __restrict__ cs,
                                               const float* __restrict__ sn,
                                               ushort_t* __restrict__ qbf,
                                               ushort_t* __restrict__ kbf)
{
    const float SC = 0.16129842f;  // (1/sqrt(80)) * log2(e)
    int idx = blockIdx.x * 256 + threadIdx.x;
    int d = idx % HALF;
    int t = (idx / HALF) % T_LEN;
    int h = idx / (HALF * T_LEN);
    float c = cs[t * HALF + d], s = sn[t * HALF + d];
    size_t base = ((size_t)h * T_LEN + t) * HD;
    float qr = bf2f(qraw[base + d]), qi = bf2f(qraw[base + d + HALF]);
    qbf[base + d]        = f2bf((qr * c - qi * s) * SC);
    qbf[base + d + HALF] = f2bf((qr * s + qi * c) * SC);
    float kr = bf2f(kraw[base + d]), ki = bf2f(kraw[base + d + HALF]);
    kbf[base + d]        = f2bf(kr * c - ki * s);
    kbf[base + d + HALF] = f2bf(kr * s + ki * c);
}

// ---------------- Flash attention: swapped QK^T, T14 async-stage, cvt_pk P ----------------
__global__ __launch_bounds__(256) void flash_mfma(const ushort_t* __restrict__ qbf,
                                                  const ushort_t* __restrict__ kbf,
                                                  const ushort_t* __restrict__ vt,
                                                  ushort_t* __restrict__ attn_bf)
{
    const int h = blockIdx.y;
    const int q0 = blockIdx.x * 64;
    const int tid = threadIdx.x;
    const int wq = tid >> 6;
    const int lane = tid & 63;
    const int g = lane >> 4;
    const int c = lane & 15;

    __shared__ ushort_t Ks[64][104];
    __shared__ ushort_t Vs[HD][72];
    __shared__ ushort_t Ps[4][16][72];

    for (int i = tid; i < 64 * 16; i += 256)
        Ks[i >> 4][80 + (i & 15)] = 0;

    // kt-invariant staging geometry: 1280 chunks of 8 ushorts, 5 per thread.
    // chunks [0,640): K tile row j/10, col (j%10)*8 ; [640,1280): V^T row jj/8, col (jj&7)*8
    int goff[5]; ushort_t* lptr[5]; bool selK[5];
    #pragma unroll
    for (int u = 0; u < 5; ++u) {
        int j = tid + u * 256;
        if (j < 640) {
            int r = j / 10, cc = (j % 10) * 8;
            goff[u] = r * HD + cc;
            lptr[u] = &Ks[r][cc];
            selK[u] = true;
        } else {
            int jj = j - 640;
            int r = jj >> 3, cc = (jj & 7) * 8;
            goff[u] = r * T_LEN + cc;
            lptr[u] = &Vs[r][cc];
            selK[u] = false;
        }
    }
    const ushort_t* gK = kbf + (size_t)h * T_LEN * HD;
    const ushort_t* gV = vt + (size_t)h * HD * T_LEN;

    short8 qf[3];
    {
        const ushort_t* qp = qbf + ((size_t)h * T_LEN + q0 + wq * 16 + c) * HD;
        #pragma unroll
        for (int ch = 0; ch < 3; ++ch) {
            int k = ch * 32 + 8 * g;
            if (k < HD) qf[ch] = *(const short8*)(qp + k);
            else        qf[ch] = (short8)(short)0;
        }
    }

    f32x4 oacc[5];
    #pragma unroll
    for (int m = 0; m < 5; ++m) oacc[m] = (f32x4)(0.f);
    float m_run = -1e30f, l_run = 0.f;

    short8 pfA[5], pfB[5];

    auto load_tile = [&](short8* pf, int ktn) {
        #pragma unroll
        for (int u = 0; u < 5; ++u)
            pf[u] = *(const short8*)((selK[u] ? gK + ktn * 64 * HD : gV + ktn * 64) + goff[u]);
    };
    auto store_tile = [&](short8* pf) {
        #pragma unroll
        for (int u = 0; u < 5; ++u)
            *(short8*)lptr[u] = pf[u];
    };

    auto body = [&](short8* pfc, short8* pfn, int kt) {
        store_tile(pfc);                      // LDS write of tile kt (vmcnt auto-waited)
        __syncthreads();                      // B1: tile visible
        int ktn = (kt + 1 < T_LEN / 64) ? kt + 1 : kt;
        load_tile(pfn, ktn);                  // prefetch kt+1: lands during compute

        // S^T = mfma(A=K_frag, B=Q_frag): lane holds S[q=c][kv=16t+4g+r]
        f32x4 s[4];
        #pragma unroll
        for (int t = 0; t < 4; ++t) {
            f32x4 acc = (f32x4)(0.f);
            #pragma unroll
            for (int ch = 0; ch < 3; ++ch) {
                short8 a = *(const short8*)&Ks[t * 16 + c][ch * 32 + 8 * g];
                acc = __builtin_amdgcn_mfma_f32_16x16x32_bf16(a, qf[ch], acc, 0, 0, 0);
            }
            s[t] = acc;
        }

        // row max: in-lane tree + cross-g combine
        float mx01 = fmaxf(fmaxf(s[0][0], s[0][1]), fmaxf(s[0][2], s[0][3]));
        float mx23 = fmaxf(fmaxf(s[1][0], s[1][1]), fmaxf(s[1][2], s[1][3]));
        float mx45 = fmaxf(fmaxf(s[2][0], s[2][1]), fmaxf(s[2][2], s[2][3]));
        float mx67 = fmaxf(fmaxf(s[3][0], s[3][1]), fmaxf(s[3][2], s[3][3]));
        float mx = fmaxf(fmaxf(mx01, mx23), fmaxf(mx45, mx67));
        mx = fmaxf(mx, __shfl_xor(mx, 16));
        mx = fmaxf(mx, __shfl_xor(mx, 32));

        // defer-max (exact): rescale only when max grew by > 11 log2-units
        float al = 1.f;
        if (!__all(mx - m_run <= 11.0f)) {
            float m_new = fmaxf(m_run, mx);
            al = __builtin_amdgcn_exp2f(m_run - m_new);
            m_run = m_new;
            #pragma unroll
            for (int r = 0; r < 4; ++r) {
                float alq = __shfl(al, 4 * g + r);
                #pragma unroll
                for (int m = 0; m < 5; ++m) oacc[m][r] *= alq;
            }
        }

        float ps = 0.f;
        #pragma unroll
        for (int t = 0; t < 4; ++t)
            #pragma unroll
            for (int r = 0; r < 4; ++r) {
                float p = __builtin_amdgcn_exp2f(s[t][r] - m_run);
                s[t][r] = p;
                ps += p;
            }
        ps += __shfl_xor(ps, 16);
        ps += __shfl_xor(ps, 32);
        l_run = l_run * al + ps;

        // P write via v_cvt_pk_bf16_f32 (T12): 8B per 16x16 tile
        #pragma unroll
        for (int t = 0; t < 4; ++t) {
            unsigned int lo, hi;
            asm("v_cvt_pk_bf16_f32 %0, %1, %2" : "=v"(lo) : "v"(s[t][0]), "v"(s[t][1]));
            asm("v_cvt_pk_bf16_f32 %0, %1, %2" : "=v"(hi) : "v"(s[t][2]), "v"(s[t][3]));
            unsigned long long pk = ((unsigned long long)hi << 32) | lo;
            *(unsigned long long*)&Ps[wq][c][t * 16 + 4 * g] = pk;
        }

        // O += P V
        #pragma unroll
        for (int ch = 0; ch < 2; ++ch) {
            short8 a = *(const short8*)&Ps[wq][c][ch * 32 + 8 * g];
            #pragma unroll
            for (int m = 0; m < 5; ++m) {
                short8 b = *(const short8*)&Vs[m * 16 + c][ch * 32 + 8 * g];
                oacc[m] = __builtin_amdgcn_mfma_f32_16x16x32_bf16(a, b, oacc[m], 0, 0, 0);
            }
        }
        __syncthreads();  // B2: all waves done reading Ks/Vs
    };

    load_tile(pfA, 0);
    for (int kt = 0; kt < T_LEN / 64; kt += 2) {
        body(pfA, pfB, kt);
        body(pfB, pfA, kt + 1);
    }

    float linv = 1.0f / l_run;
    #pragma unroll
    for (int r = 0; r < 4; ++r) {
        float liq = __shfl(linv, 4 * g + r);
        int t = q0 + wq * 16 + 4 * g + r;
        #pragma unroll
        for (int m = 0; m < 5; ++m)
            attn_bf[(size_t)t * D_MODEL + h * HD + m * 16 + c] = f2bf(oacc[m][r] * liq);
    }
}

// ---------------- GEMM2 (bf16 MFMA): out = attn @ Wo + bo, fp32 out ----------------
__global__ __launch_bounds__(256) void gemm_out_mfma(const ushort_t* __restrict__ Abf,
                                                     const ushort_t* __restrict__ Bt,
                                                     const float* __restrict__ bias,
                                                     float* __restrict__ C)
{
    __shared__ ushort_t As[128 * 32];
    __shared__ ushort_t Bs[128 * 32];
    const int tid = threadIdx.x;
    const int wave = tid >> 6, lane = tid & 63;
    const int g = lane >> 4, c = lane & 15;
    const int wr = wave >> 1, wc = wave & 1;
    const int m0 = blockIdx.y * 128, n0 = blockIdx.x * 128;
    const int K = D_MODEL;

    f32x4 acc[4][4];
    #pragma unroll
    for (int i = 0; i < 4; ++i)
        #pragma unroll
        for (int j = 0; j < 4; ++j) acc[i][j] = (f32x4)(0.f);

    for (int k0 = 0; k0 < K; k0 += 32) {
        #pragma unroll
        for (int q = 0; q < 2; ++q) {
            int j = wave * 128 + q * 64 + lane;
            int row = j >> 2, col8 = (j & 3) * 8;
            GLOAD16(Abf + (size_t)(m0 + row) * K + k0 + col8, &As[(wave * 2 + q) * 512]);
            GLOAD16(Bt  + (size_t)(n0 + row) * K + k0 + col8, &Bs[(wave * 2 + q) * 512]);
        }
        __syncthreads();

        short8 a[4], b[4];
        #pragma unroll
        for (int mi = 0; mi < 4; ++mi)
            a[mi] = *(const short8*)&As[(wr * 64 + mi * 16 + c) * 32 + g * 8];
        #pragma unroll
        for (int ni = 0; ni < 4; ++ni)
            b[ni] = *(const short8*)&Bs[(wc * 64 + ni * 16 + c) * 32 + g * 8];
        #pragma unroll
        for (int mi = 0; mi < 4; ++mi)
            #pragma unroll
            for (int ni = 0; ni < 4; ++ni)
                acc[mi][ni] = __builtin_amdgcn_mfma_f32_16x16x32_bf16(a[mi], b[ni], acc[mi][ni], 0, 0, 0);
        __syncthreads();
    }

    #pragma unroll
    for (int mi = 0; mi < 4; ++mi) {
        int tbase = m0 + wr * 64 + mi * 16 + 4 * g;
        #pragma unroll
        for (int ni = 0; ni < 4; ++ni) {
            int n = n0 + wc * 64 + ni * 16 + c;
            float bv = bias[n];
            #pragma unroll
            for (int r = 0; r < 4; ++r)
                C[(size_t)(tbase + r) * D_MODEL + n] = acc[mi][ni][r] + bv;
        }
    }
}

extern "C" void kernel_launch(void* const* d_in, const int* in_sizes, int n_in,
                              void* d_out, int out_size, void* d_ws, size_t ws_size,
                              hipStream_t stream)
{
    const float* x    = (const float*)d_in[0];
    const float* rope = (const float*)d_in[1];
    const float* Wqkv = (const float*)d_in[2];
    const float* bqkv = (const float*)d_in[3];
    const float* Wo   = (const float*)d_in[4];
    const float* bo   = (const float*)d_in[5];
    float* out = (float*)d_out;
    float* ws  = (float*)d_ws;

    const size_t per2 = 2621440;   // one [H][T][80] bf16 buffer, in float units
    const size_t wt_f = 2457600;   // Wqkv_t bf16 in float units
    const size_t tab  = (size_t)T_LEN * HALF;

    ushort_t* qraw = (ushort_t*)ws;
    ushort_t* kraw = (ushort_t*)(ws + per2);
    ushort_t* vt   = (ushort_t*)(ws + 2 * per2);
    ushort_t* xbf  = (ushort_t*)(ws + 3 * per2);
    ushort_t* Wt   = (ushort_t*)(ws + 4 * per2);
    float*    cs   = ws + 4 * per2 + wt_f;
    float*    sn   = cs + tab;
    ushort_t* qbf  = (ushort_t*)(sn + tab);
    ushort_t* kbf  = (ushort_t*)(sn + tab + per2);
    ushort_t* attn_bf = qraw;
    ushort_t* Wo_t = qbf;

    rope_table<<<(T_LEN * HALF + 255) / 256, 256, 0, stream>>>(rope, cs, sn);

    cvt_bf16<<<(T_LEN * D_MODEL) / 1024, 256, 0, stream>>>(x, xbf);

    transpose_cvt<<<dim3(N_QKV / 64, D_MODEL / 64), 256, 0, stream>>>(Wqkv, Wt, D_MODEL, N_QKV);

    gemm_qkv_mfma<<<dim3(N_QKV / 128, T_LEN / 128), 256, 0, stream>>>(xbf, Wt, bqkv, qraw, kraw, vt);

    qk_prep<<<(H_NUM * T_LEN * HALF) / 256, 256, 0, stream>>>(qraw, kraw, cs, sn, qbf, kbf);

    flash_mfma<<<dim3(T_LEN / 64, H_NUM), 256, 0, stream>>>(qbf, kbf, vt, attn_bf);

    transpose_cvt<<<dim3(D_MODEL / 64, D_MODEL / 64), 256, 0, stream>>>(Wo, Wo_t, D_MODEL, D_MODEL);

    gemm_out_mfma<<<dim3(D_MODEL / 128, T_LEN / 128), 256, 0, stream>>>(attn_bf, Wo_t, bo, out);
}

// Round 8
// 292.812 us; speedup vs baseline: 24.7702x; 1.0582x over previous
//
#include <hip/hip_runtime.h>
#include <math.h>

#define T_LEN 4096
#define D_MODEL 1280
#define H_NUM 16
#define HD 80
#define HALF 40
#define N_QKV (3*D_MODEL)

typedef short short8 __attribute__((ext_vector_type(8)));
typedef short short4v __attribute__((ext_vector_type(4)));
typedef float f32x4 __attribute__((ext_vector_type(4)));
typedef float f32x16 __attribute__((ext_vector_type(16)));
typedef float float4v __attribute__((ext_vector_type(4)));
typedef unsigned int uint4v __attribute__((ext_vector_type(4)));
typedef unsigned short ushort_t;

static __device__ __forceinline__ unsigned short f2bf(float f) {
    unsigned int u = __builtin_bit_cast(unsigned int, f);
    unsigned int r = (u + 0x7FFFu + ((u >> 16) & 1u)) >> 16;
    return (unsigned short)r;
}
static __device__ __forceinline__ float bf2f(unsigned short u) {
    return __builtin_bit_cast(float, (unsigned int)u << 16);
}

#define GLOAD16(gp, lp) \
    __builtin_amdgcn_global_load_lds((const __attribute__((address_space(1))) void*)(gp), \
                                     (__attribute__((address_space(3))) void*)(lp), 16, 0, 0)

// ---------------- rope tables ----------------
__global__ void rope_table(const float* __restrict__ rope,
                           float* __restrict__ cs, float* __restrict__ sn)
{
    int i = blockIdx.x * 256 + threadIdx.x;
    if (i < T_LEN * HALF) {
        float a = rope[i];
        cs[i] = cosf(a);
        sn[i] = sinf(a);
    }
}

// ---------------- fp32 -> bf16 elementwise (n % 1024 == 0) ----------------
__global__ __launch_bounds__(256) void cvt_bf16(const float* __restrict__ in,
                                                ushort_t* __restrict__ out)
{
    int i = (blockIdx.x * 256 + threadIdx.x) * 4;
    float4v v = *(const float4v*)&in[i];
    short4v o;
    o[0] = (short)f2bf(v[0]); o[1] = (short)f2bf(v[1]);
    o[2] = (short)f2bf(v[2]); o[3] = (short)f2bf(v[3]);
    *(short4v*)&out[i] = o;
}

// ---------------- fp32 [R][C] -> bf16 [C][R] transpose ----------------
__global__ __launch_bounds__(256) void transpose_cvt(const float* __restrict__ in,
                                                     ushort_t* __restrict__ out,
                                                     int R, int C)
{
    __shared__ float tile[64][65];
    int r0 = blockIdx.y * 64, c0 = blockIdx.x * 64;
    int tid = threadIdx.x;
    for (int i = tid; i < 4096; i += 256) {
        int r = i >> 6, c = i & 63;
        tile[r][c] = in[(size_t)(r0 + r) * C + c0 + c];
    }
    __syncthreads();
    for (int i = tid; i < 4096; i += 256) {
        int r = i >> 6, c = i & 63;
        out[(size_t)(c0 + r) * R + r0 + c] = f2bf(tile[c][r]);
    }
}

// ---------------- GEMM1 (bf16 MFMA, m97 structure): qkv = x @ Wqkv + b ----------------
__global__ __launch_bounds__(256) void gemm_qkv_mfma(const ushort_t* __restrict__ xbf,
                                                     const ushort_t* __restrict__ Wt,
                                                     const float* __restrict__ bias,
                                                     ushort_t* __restrict__ qraw,
                                                     ushort_t* __restrict__ kraw,
                                                     ushort_t* __restrict__ vt)
{
    __shared__ ushort_t As[128 * 32];
    __shared__ ushort_t Bs[128 * 32];
    const int tid = threadIdx.x;
    const int wave = tid >> 6, lane = tid & 63;
    const int g = lane >> 4, c = lane & 15;
    const int wr = wave >> 1, wc = wave & 1;
    const int m0 = blockIdx.y * 128, n0 = blockIdx.x * 128;
    const int K = D_MODEL;

    f32x4 acc[4][4];
    #pragma unroll
    for (int i = 0; i < 4; ++i)
        #pragma unroll
        for (int j = 0; j < 4; ++j) acc[i][j] = (f32x4)(0.f);

    for (int k0 = 0; k0 < K; k0 += 32) {
        #pragma unroll
        for (int q = 0; q < 2; ++q) {
            int j = wave * 128 + q * 64 + lane;
            int row = j >> 2, col8 = (j & 3) * 8;
            GLOAD16(xbf + (size_t)(m0 + row) * K + k0 + col8, &As[(wave * 2 + q) * 512]);
            GLOAD16(Wt  + (size_t)(n0 + row) * K + k0 + col8, &Bs[(wave * 2 + q) * 512]);
        }
        __syncthreads();

        short8 a[4], b[4];
        #pragma unroll
        for (int mi = 0; mi < 4; ++mi)
            a[mi] = *(const short8*)&As[(wr * 64 + mi * 16 + c) * 32 + g * 8];
        #pragma unroll
        for (int ni = 0; ni < 4; ++ni)
            b[ni] = *(const short8*)&Bs[(wc * 64 + ni * 16 + c) * 32 + g * 8];
        #pragma unroll
        for (int mi = 0; mi < 4; ++mi)
            #pragma unroll
            for (int ni = 0; ni < 4; ++ni)
                acc[mi][ni] = __builtin_amdgcn_mfma_f32_16x16x32_bf16(a[mi], b[ni], acc[mi][ni], 0, 0, 0);
        __syncthreads();
    }

    const int sel = n0 / D_MODEL;
    #pragma unroll
    for (int mi = 0; mi < 4; ++mi) {
        int tbase = m0 + wr * 64 + mi * 16 + 4 * g;
        #pragma unroll
        for (int ni = 0; ni < 4; ++ni) {
            int n = n0 + wc * 64 + ni * 16 + c;
            float bv = bias[n];
            int rem = n - sel * D_MODEL;
            int h = rem / HD, d = rem % HD;
            if (sel < 2) {
                ushort_t* dst = sel ? kraw : qraw;
                #pragma unroll
                for (int r = 0; r < 4; ++r)
                    dst[((size_t)h * T_LEN + tbase + r) * HD + d] = f2bf(acc[mi][ni][r] + bv);
            } else {
                short4v o;
                #pragma unroll
                for (int r = 0; r < 4; ++r) o[r] = (short)f2bf(acc[mi][ni][r] + bv);
                *(short4v*)&vt[((size_t)h * HD + d) * T_LEN + tbase] = o;
            }
        }
    }
}

// ---------------- rope on raw bf16 q,k; q gets scale*log2e folded in ----------------
__global__ __launch_bounds__(256) void qk_prep(const ushort_t* __restrict__ qraw,
                                               const ushort_t* __restrict__ kraw,
                                               const float* __restrict__ cs,
                                               const float* __restrict__ sn,
                                               ushort_t* __restrict__ qbf,
                                               ushort_t* __restrict__ kbf)
{
    const float SC = 0.16129842f;  // (1/sqrt(80)) * log2(e)
    int idx = blockIdx.x * 256 + threadIdx.x;
    int d = idx % HALF;
    int t = (idx / HALF) % T_LEN;
    int h = idx / (HALF * T_LEN);
    float c = cs[t * HALF + d], s = sn[t * HALF + d];
    size_t base = ((size_t)h * T_LEN + t) * HD;
    float qr = bf2f(qraw[base + d]), qi = bf2f(qraw[base + d + HALF]);
    qbf[base + d]        = f2bf((qr * c - qi * s) * SC);
    qbf[base + d + HALF] = f2bf((qr * s + qi * c) * SC);
    float kr = bf2f(kraw[base + d]), ki = bf2f(kraw[base + d + HALF]);
    kbf[base + d]        = f2bf(kr * c - ki * s);
    kbf[base + d + HALF] = f2bf(kr * s + ki * c);
}

// ---------------- Flash attention: 32x32x16 MFMA, in-register P via permlane ----------------
// 2 waves/block, 32 q-rows/wave, KV tile 64.
// Swapped S^T = mfma(A=K, B=Q): lane holds S[kv=32*tau+crow(reg,hi)][q=ln],
//   crow(reg,hi) = (reg&3)+8*(reg>>2)+4*hi  (C/D map verified m74/m101).
// PV A-frag built in-register: X[k]=cvt_pk(s[2k],s[2k+1]) then
//   permlane32_swap(vdst=Xlow, vsrc=Xhigh) — vdst.hi <-> vsrc.lo — pairs
//   (X0,X2),(X1,X3),(X4,X6),(X5,X7): X0->w0,(0,1)/(8,9); X2->w2,(4,5)/(12,13); etc.
__global__ __launch_bounds__(128) void flash_mfma(const ushort_t* __restrict__ qbf,
                                                  const ushort_t* __restrict__ kbf,
                                                  const ushort_t* __restrict__ vt,
                                                  ushort_t* __restrict__ attn_bf)
{
    const int h = blockIdx.y;
    const int q0 = blockIdx.x * 64;
    const int tid = threadIdx.x;
    const int wq = tid >> 6;        // wave: q rows q0 + wq*32 ..
    const int lane = tid & 63;
    const int hi = lane >> 5;
    const int ln = lane & 31;

    __shared__ ushort_t Ks[64][88];   // [kv][k 0..79]
    __shared__ ushort_t Vs[96][72];   // [f 0..95][kv 0..63], rows 80..95 zero

    for (int i = tid; i < 16 * 72; i += 128)
        Vs[80 + i / 72][i % 72] = 0;

    // kt-invariant staging geometry: 10 chunks of 8 ushorts per thread
    int goff[10]; ushort_t* lptr[10];
    #pragma unroll
    for (int u = 0; u < 10; ++u) {
        if (u < 5) {
            int j = tid + u * 128;               // 640 K-chunks: 64 rows x 80
            int r = j / 10, cc = (j % 10) * 8;
            goff[u] = r * HD + cc; lptr[u] = &Ks[r][cc];
        } else {
            int j = tid + (u - 5) * 128;         // 640 V-chunks: 80 rows x 64
            int r = j >> 3, cc = (j & 7) * 8;
            goff[u] = r * T_LEN + cc; lptr[u] = &Vs[r][cc];
        }
    }
    const ushort_t* gK = kbf + (size_t)h * T_LEN * HD;
    const ushort_t* gV = vt + (size_t)h * HD * T_LEN;

    // Q fragments (B-operand): col=ln, k = ch*16 + 8*hi + i  (K=80 exact, 5 chunks)
    short8 qf[5];
    {
        const ushort_t* qp = qbf + ((size_t)h * T_LEN + q0 + wq * 32 + ln) * HD + 8 * hi;
        #pragma unroll
        for (int ch = 0; ch < 5; ++ch) qf[ch] = *(const short8*)(qp + ch * 16);
    }

    f32x16 oacc[3];
    #pragma unroll
    for (int ft = 0; ft < 3; ++ft) oacc[ft] = (f32x16)(0.f);
    float m_run = -1e30f, l_run = 0.f;

    short8 pf[10];
    auto load_tile = [&](int ktn) {
        const ushort_t* bK = gK + ktn * 64 * HD;
        const ushort_t* bV = gV + ktn * 64;
        #pragma unroll
        for (int u = 0; u < 10; ++u)
            pf[u] = *(const short8*)((u < 5 ? bK : bV) + goff[u]);
    };

    load_tile(0);
    for (int kt = 0; kt < T_LEN / 64; ++kt) {
        #pragma unroll
        for (int u = 0; u < 10; ++u) *(short8*)lptr[u] = pf[u];
        __syncthreads();                         // tile kt visible
        load_tile(kt < T_LEN / 64 - 1 ? kt + 1 : kt);   // prefetch lands during compute

        // S^T: two 32x32 kv-tiles, K=80 in 5 chunks
        f32x16 st0 = (f32x16)(0.f), st1 = (f32x16)(0.f);
        #pragma unroll
        for (int ch = 0; ch < 5; ++ch) {
            short8 a0 = *(const short8*)&Ks[ln][ch * 16 + 8 * hi];
            st0 = __builtin_amdgcn_mfma_f32_32x32x16_bf16(a0, qf[ch], st0, 0, 0, 0);
        }
        #pragma unroll
        for (int ch = 0; ch < 5; ++ch) {
            short8 a1 = *(const short8*)&Ks[32 + ln][ch * 16 + 8 * hi];
            st1 = __builtin_amdgcn_mfma_f32_32x32x16_bf16(a1, qf[ch], st1, 0, 0, 0);
        }

        // row max: 32 in-lane + cross-half combine (q = ln owned by lane & lane^32)
        float mx = st0[0];
        #pragma unroll
        for (int i = 1; i < 16; ++i) mx = fmaxf(mx, st0[i]);
        #pragma unroll
        for (int i = 0; i < 16; ++i) mx = fmaxf(mx, st1[i]);
        mx = fmaxf(mx, __shfl_xor(mx, 32));

        // defer-max (exact): rescale only when max grew > 11 log2-units
        float al = 1.f;
        if (!__all(mx - m_run <= 11.0f)) {
            float m_new = fmaxf(m_run, mx);
            al = __builtin_amdgcn_exp2f(m_run - m_new);
            m_run = m_new;
            #pragma unroll
            for (int reg = 0; reg < 16; ++reg) {
                float alq = __shfl(al, (reg & 3) + 8 * (reg >> 2) + 4 * hi);
                oacc[0][reg] *= alq; oacc[1][reg] *= alq; oacc[2][reg] *= alq;
            }
        }

        float ps = 0.f;
        #pragma unroll
        for (int i = 0; i < 16; ++i) { st0[i] = __builtin_amdgcn_exp2f(st0[i] - m_run); ps += st0[i]; }
        #pragma unroll
        for (int i = 0; i < 16; ++i) { st1[i] = __builtin_amdgcn_exp2f(st1[i] - m_run); ps += st1[i]; }
        ps += __shfl_xor(ps, 32);
        l_run = l_run * al + ps;

        // P -> bf16 A-frags fully in-register (T12)
        unsigned int X[8], Y[8];
        #pragma unroll
        for (int k = 0; k < 8; ++k) {
            asm("v_cvt_pk_bf16_f32 %0, %1, %2" : "=v"(X[k]) : "v"(st0[2 * k]), "v"(st0[2 * k + 1]));
            asm("v_cvt_pk_bf16_f32 %0, %1, %2" : "=v"(Y[k]) : "v"(st1[2 * k]), "v"(st1[2 * k + 1]));
        }
        // vdst = low-kv-group word, vsrc = +8kv word: vdst.hi <-> vsrc.lo
        asm volatile("v_permlane32_swap_b32 %0, %1" : "+v"(X[0]), "+v"(X[2]));
        asm volatile("v_permlane32_swap_b32 %0, %1" : "+v"(X[1]), "+v"(X[3]));
        asm volatile("v_permlane32_swap_b32 %0, %1" : "+v"(X[4]), "+v"(X[6]));
        asm volatile("v_permlane32_swap_b32 %0, %1" : "+v"(X[5]), "+v"(X[7]));
        asm volatile("v_permlane32_swap_b32 %0, %1" : "+v"(Y[0]), "+v"(Y[2]));
        asm volatile("v_permlane32_swap_b32 %0, %1" : "+v"(Y[1]), "+v"(Y[3]));
        asm volatile("v_permlane32_swap_b32 %0, %1" : "+v"(Y[4]), "+v"(Y[6]));
        asm volatile("v_permlane32_swap_b32 %0, %1" : "+v"(Y[5]), "+v"(Y[7]));

        short8 pfrag[4];
        {
            uint4v u0 = {X[0], X[1], X[2], X[3]};
            uint4v u1 = {X[4], X[5], X[6], X[7]};
            uint4v u2 = {Y[0], Y[1], Y[2], Y[3]};
            uint4v u3 = {Y[4], Y[5], Y[6], Y[7]};
            pfrag[0] = __builtin_bit_cast(short8, u0);
            pfrag[1] = __builtin_bit_cast(short8, u1);
            pfrag[2] = __builtin_bit_cast(short8, u2);
            pfrag[3] = __builtin_bit_cast(short8, u3);
        }

        // O += P V : 3 f-tiles (f 0..95, rows 80..95 zero), 4 kv-chunks
        #pragma unroll
        for (int ch = 0; ch < 4; ++ch) {
            #pragma unroll
            for (int ft = 0; ft < 3; ++ft) {
                short8 b = *(const short8*)&Vs[ft * 32 + ln][ch * 16 + 8 * hi];
                oacc[ft] = __builtin_amdgcn_mfma_f32_32x32x16_bf16(pfrag[ch], b, oacc[ft], 0, 0, 0);
            }
        }
        __syncthreads();                         // all waves done reading Ks/Vs
    }

    float linv = 1.0f / l_run;
    #pragma unroll
    for (int reg = 0; reg < 16; ++reg) {
        int q = (reg & 3) + 8 * (reg >> 2) + 4 * hi;
        float liq = __shfl(linv, q);
        size_t rb = (size_t)(q0 + wq * 32 + q) * D_MODEL + h * HD;
        attn_bf[rb + ln]      = f2bf(oacc[0][reg] * liq);
        attn_bf[rb + 32 + ln] = f2bf(oacc[1][reg] * liq);
        if (ln < 16)
            attn_bf[rb + 64 + ln] = f2bf(oacc[2][reg] * liq);
    }
}

// ---------------- GEMM2 (bf16 MFMA): out = attn @ Wo + bo, fp32 out ----------------
__global__ __launch_bounds__(256) void gemm_out_mfma(const ushort_t* __restrict__ Abf,
                                                     const ushort_t* __restrict__ Bt,
                                                     const float* __restrict__ bias,
                                                     float* __restrict__ C)
{
    __shared__ ushort_t As[128 * 32];
    __shared__ ushort_t Bs[128 * 32];
    const int tid = threadIdx.x;
    const int wave = tid >> 6, lane = tid & 63;
    const int g = lane >> 4, c = lane & 15;
    const int wr = wave >> 1, wc = wave & 1;
    const int m0 = blockIdx.y * 128, n0 = blockIdx.x * 128;
    const int K = D_MODEL;

    f32x4 acc[4][4];
    #pragma unroll
    for (int i = 0; i < 4; ++i)
        #pragma unroll
        for (int j = 0; j < 4; ++j) acc[i][j] = (f32x4)(0.f);

    for (int k0 = 0; k0 < K; k0 += 32) {
        #pragma unroll
        for (int q = 0; q < 2; ++q) {
            int j = wave * 128 + q * 64 + lane;
            int row = j >> 2, col8 = (j & 3) * 8;
            GLOAD16(Abf + (size_t)(m0 + row) * K + k0 + col8, &As[(wave * 2 + q) * 512]);
            GLOAD16(Bt  + (size_t)(n0 + row) * K + k0 + col8, &Bs[(wave * 2 + q) * 512]);
        }
        __syncthreads();

        short8 a[4], b[4];
        #pragma unroll
        for (int mi = 0; mi < 4; ++mi)
            a[mi] = *(const short8*)&As[(wr * 64 + mi * 16 + c) * 32 + g * 8];
        #pragma unroll
        for (int ni = 0; ni < 4; ++ni)
            b[ni] = *(const short8*)&Bs[(wc * 64 + ni * 16 + c) * 32 + g * 8];
        #pragma unroll
        for (int mi = 0; mi < 4; ++mi)
            #pragma unroll
            for (int ni = 0; ni < 4; ++ni)
                acc[mi][ni] = __builtin_amdgcn_mfma_f32_16x16x32_bf16(a[mi], b[ni], acc[mi][ni], 0, 0, 0);
        __syncthreads();
    }

    #pragma unroll
    for (int mi = 0; mi < 4; ++mi) {
        int tbase = m0 + wr * 64 + mi * 16 + 4 * g;
        #pragma unroll
        for (int ni = 0; ni < 4; ++ni) {
            int n = n0 + wc * 64 + ni * 16 + c;
            float bv = bias[n];
            #pragma unroll
            for (int r = 0; r < 4; ++r)
                C[(size_t)(tbase + r) * D_MODEL + n] = acc[mi][ni][r] + bv;
        }
    }
}

extern "C" void kernel_launch(void* const* d_in, const int* in_sizes, int n_in,
                              void* d_out, int out_size, void* d_ws, size_t ws_size,
                              hipStream_t stream)
{
    const float* x    = (const float*)d_in[0];
    const float* rope = (const float*)d_in[1];
    const float* Wqkv = (const float*)d_in[2];
    const float* bqkv = (const float*)d_in[3];
    const float* Wo   = (const float*)d_in[4];
    const float* bo   = (const float*)d_in[5];
    float* out = (float*)d_out;
    float* ws  = (float*)d_ws;

    const size_t per2 = 2621440;   // one [H][T][80] bf16 buffer, in float units
    const size_t wt_f = 2457600;   // Wqkv_t bf16 in float units
    const size_t tab  = (size_t)T_LEN * HALF;

    ushort_t* qraw = (ushort_t*)ws;
    ushort_t* kraw = (ushort_t*)(ws + per2);
    ushort_t* vt   = (ushort_t*)(ws + 2 * per2);
    ushort_t* xbf  = (ushort_t*)(ws + 3 * per2);
    ushort_t* Wt   = (ushort_t*)(ws + 4 * per2);
    float*    cs   = ws + 4 * per2 + wt_f;
    float*    sn   = cs + tab;
    ushort_t* qbf  = (ushort_t*)(sn + tab);
    ushort_t* kbf  = (ushort_t*)(sn + tab + per2);
    ushort_t* attn_bf = qraw;
    ushort_t* Wo_t = qbf;

    rope_table<<<(T_LEN * HALF + 255) / 256, 256, 0, stream>>>(rope, cs, sn);

    cvt_bf16<<<(T_LEN * D_MODEL) / 1024, 256, 0, stream>>>(x, xbf);

    transpose_cvt<<<dim3(N_QKV / 64, D_MODEL / 64), 256, 0, stream>>>(Wqkv, Wt, D_MODEL, N_QKV);

    gemm_qkv_mfma<<<dim3(N_QKV / 128, T_LEN / 128), 256, 0, stream>>>(xbf, Wt, bqkv, qraw, kraw, vt);

    qk_prep<<<(H_NUM * T_LEN * HALF) / 256, 256, 0, stream>>>(qraw, kraw, cs, sn, qbf, kbf);

    flash_mfma<<<dim3(T_LEN / 64, H_NUM), 128, 0, stream>>>(qbf, kbf, vt, attn_bf);

    transpose_cvt<<<dim3(D_MODEL / 64, D_MODEL / 64), 256, 0, stream>>>(Wo, Wo_t, D_MODEL, D_MODEL);

    gemm_out_mfma<<<dim3(D_MODEL / 128, T_LEN / 128), 256, 0, stream>>>(attn_bf, Wo_t, bo, out);
}